// Round 2
// baseline (741.927 us; speedup 1.0000x reference)
//
#include <hip/hip_runtime.h>
#include <hip/hip_bf16.h>

typedef __hip_bfloat16 bf16;

__device__ __forceinline__ float bf2f(bf16 v){ return __bfloat162float(v); }
__device__ __forceinline__ bf16  f2bf(float f){ return __float2bfloat16(f); }
__device__ __forceinline__ float lrelu(float a){ return a > 0.f ? a : 0.2f*a; }

// ---------------- dtype detection ----------------
// Sample even-indexed 16-bit words of `high`. bf16 data: valid exponents.
// f32 data: these are low-mantissa halves -> random exponent field.
__global__ void k_detect(const unsigned short* __restrict__ raw, int* __restrict__ flag){
    int t = threadIdx.x; // 256
    unsigned short w = raw[2*t];
    int e = (w >> 7) & 0xFF;
    int ok = (e >= 90 && e <= 140) ? 1 : 0;
    __shared__ int cnt;
    if (t == 0) cnt = 0;
    __syncthreads();
    atomicAdd(&cnt, ok);
    __syncthreads();
    if (t == 0) *flag = (cnt >= 192) ? 1 : 0;  // 1 = bf16, 0 = f32
}

// ---------------- convert all float tensors to canonical bf16 ----------------
struct ConvArgs {
    const void* src[12];
    bf16* dst[12];
    int n[12];
};

__global__ __launch_bounds__(256) void k_convert(ConvArgs a, const int* __restrict__ flag){
    int ten = blockIdx.y;
    int n = a.n[ten];
    int isb = *flag;
    const void* s = a.src[ten];
    bf16* d = a.dst[ten];
    for (int i = blockIdx.x*256 + threadIdx.x; i < n; i += gridDim.x*256){
        if (isb) d[i] = ((const bf16*)s)[i];
        else     d[i] = f2bf(((const float*)s)[i]);
    }
}

// ---------------- CSR build ----------------
__global__ void k_zero(int* __restrict__ p, int n){
    int i = blockIdx.x*256 + threadIdx.x;
    if (i < n) p[i] = 0;
}

__global__ void k_count(const int* __restrict__ ei, int E, int N, int* __restrict__ counts){
    int i = blockIdx.x*256 + threadIdx.x;
    int tot = E + N;
    if (i < tot){
        int dst = (i < E) ? ei[E + i] : (i - E);
        atomicAdd(&counts[dst], 1);
    }
}

__global__ __launch_bounds__(1024) void k_scan(const int* __restrict__ counts,
        int* __restrict__ rowptr, int* __restrict__ cursor, int n){
    __shared__ int sd[1024];
    __shared__ int carry;
    int t = threadIdx.x;
    if (t == 0) carry = 0;
    __syncthreads();
    for (int base = 0; base < n; base += 1024){
        int i = base + t;
        int v = (i < n) ? counts[i] : 0;
        sd[t] = v;
        __syncthreads();
        for (int off = 1; off < 1024; off <<= 1){
            int a = (t >= off) ? sd[t - off] : 0;
            __syncthreads();
            sd[t] += a;
            __syncthreads();
        }
        int incl = sd[t];
        int excl = incl - v;
        if (i < n){ int r = carry + excl; rowptr[i] = r; cursor[i] = r; }
        __syncthreads();
        if (t == 1023) carry += incl;
        __syncthreads();
    }
    if (t == 0) rowptr[n] = carry;
}

__global__ void k_scatter(const int* __restrict__ ei, int E, int N,
        int* __restrict__ cursor, int* __restrict__ srcs){
    int i = blockIdx.x*256 + threadIdx.x;
    int tot = E + N;
    if (i < tot){
        int src, dst;
        if (i < E){ src = ei[i]; dst = ei[E + i]; }
        else      { src = i - E; dst = i - E; }
        int pos = atomicAdd(&cursor[dst], 1);
        srcs[pos] = src;
    }
}

// ---------------- GEMM1 (fused embedding): h1[N,256] = [high | elu(low@Wemb+bemb)] @ W1 ----------------
__global__ __launch_bounds__(256) void k_gemm1(const bf16* __restrict__ high,
        const bf16* __restrict__ low, const bf16* __restrict__ Wemb,
        const bf16* __restrict__ bemb, const bf16* __restrict__ W1,
        bf16* __restrict__ h1, int N){
    __shared__ float xs[64*192];      // 48 KB
    __shared__ float wem[32*64 + 64]; // Wemb (f32) + bemb at [2048..]
    __shared__ bf16  lows[64*32];
    int t = threadIdx.x;
    int m0 = blockIdx.x * 64;
    int rows = N - m0; if (rows > 64) rows = 64;

    // stage Wemb + bemb
    for (int i = t; i < 2048; i += 256) wem[i] = bf2f(Wemb[i]);
    if (t < 64) wem[2048 + t] = bf2f(bemb[t]);
    // stage low tile (zero-pad tail rows)
    for (int i = t; i < 64*32; i += 256)
        lows[i] = (i < rows*32) ? low[(size_t)m0*32 + i] : f2bf(0.f);
    // stage high part of x (zero-pad tail rows)
    for (int i = t; i < 64*128; i += 256){
        int r = i >> 7, c = i & 127;
        xs[r*192 + c] = (r < rows) ? bf2f(high[(size_t)(m0 + r)*128 + c]) : 0.f;
    }
    __syncthreads();

    // embedding: thread t computes row r = t&63, cols cb..cb+15
    {
        int r = t & 63;
        int cb = (t >> 6) * 16;
        float acc[16];
        #pragma unroll
        for (int j = 0; j < 16; j++) acc[j] = wem[2048 + cb + j];
        for (int k = 0; k < 32; k++){
            float lv = bf2f(lows[r*32 + k]);
            #pragma unroll
            for (int j = 0; j < 16; j++) acc[j] += lv * wem[k*64 + cb + j];
        }
        #pragma unroll
        for (int j = 0; j < 16; j++){
            float v = acc[j];
            xs[r*192 + 128 + cb + j] = v > 0.f ? v : expm1f(v);
        }
    }
    __syncthreads();

    // GEMM: 8x8 per thread
    int tn = t & 31, tm = t >> 5;
    float acc[8][8];
    #pragma unroll
    for (int i = 0; i < 8; i++)
        #pragma unroll
        for (int j = 0; j < 8; j++) acc[i][j] = 0.f;
    const bf16* wp = W1 + tn*8;
    const float* xb = xs + (tm*8)*192;
    for (int k = 0; k < 192; k++){
        float xv[8];
        #pragma unroll
        for (int i = 0; i < 8; i++) xv[i] = xb[i*192 + k];
        uint4 w = *(const uint4*)(wp + (size_t)k*256);
        float wv[8];
        union{unsigned int u; float f;} cv;
        cv.u = (w.x & 0xffffu) << 16; wv[0] = cv.f;
        cv.u = (w.x & 0xffff0000u);   wv[1] = cv.f;
        cv.u = (w.y & 0xffffu) << 16; wv[2] = cv.f;
        cv.u = (w.y & 0xffff0000u);   wv[3] = cv.f;
        cv.u = (w.z & 0xffffu) << 16; wv[4] = cv.f;
        cv.u = (w.z & 0xffff0000u);   wv[5] = cv.f;
        cv.u = (w.w & 0xffffu) << 16; wv[6] = cv.f;
        cv.u = (w.w & 0xffff0000u);   wv[7] = cv.f;
        #pragma unroll
        for (int i = 0; i < 8; i++)
            #pragma unroll
            for (int j = 0; j < 8; j++)
                acc[i][j] += xv[i] * wv[j];
    }
    #pragma unroll
    for (int i = 0; i < 8; i++){
        int m = m0 + tm*8 + i;
        if (m < N){
            #pragma unroll
            for (int j = 0; j < 8; j++)
                h1[(size_t)m*256 + tn*8 + j] = f2bf(acc[i][j]);
        }
    }
}

// ---------------- attention scalars layer 1 ----------------
__global__ __launch_bounds__(256) void k_att1(const bf16* __restrict__ h1,
        const bf16* __restrict__ attS, const bf16* __restrict__ attD,
        float* __restrict__ a_s, float* __restrict__ a_d, int N){
    int n = blockIdx.x;
    int t = threadIdx.x;
    float v = bf2f(h1[(size_t)n*256 + t]);
    float ps = v * bf2f(attS[t]);
    float pd = v * bf2f(attD[t]);
    #pragma unroll
    for (int m = 1; m < 32; m <<= 1){
        ps += __shfl_xor(ps, m);
        pd += __shfl_xor(pd, m);
    }
    if ((t & 31) == 0){
        a_s[n*8 + (t >> 5)] = ps;
        a_d[n*8 + (t >> 5)] = pd;
    }
}

// ---------------- layer-1 edge softmax + aggregation + elu + bias -> x2 (bf16) ----------------
__global__ __launch_bounds__(256) void k_edge1(const int* __restrict__ rowptr,
        const int* __restrict__ srcs, const float* __restrict__ a_s,
        const float* __restrict__ a_d, const bf16* __restrict__ h1,
        const bf16* __restrict__ b1, bf16* __restrict__ x2, int N){
    __shared__ float ad[8], sm[8], srz[8];
    __shared__ float wred[4][8];
    __shared__ float wbuf[32][8];
    __shared__ int   sbuf[32];
    int n = blockIdx.x;
    int t = threadIdx.x;
    int beg = rowptr[n], end = rowptr[n+1];
    int deg = end - beg;
    if (t < 8) ad[t] = a_d[n*8 + t];
    __syncthreads();
    int h = t & 7;
    float adh = ad[h];
    int lane = t & 63, wv = t >> 6;
    // pass 1: per-head max
    float lmax = -1e30f;
    for (int i = t; i < deg*8; i += 256){
        int e = i >> 3;
        int s = srcs[beg + e];
        lmax = fmaxf(lmax, lrelu(a_s[s*8 + h] + adh));
    }
    lmax = fmaxf(lmax, __shfl_xor(lmax, 8));
    lmax = fmaxf(lmax, __shfl_xor(lmax, 16));
    lmax = fmaxf(lmax, __shfl_xor(lmax, 32));
    if (lane < 8) wred[wv][lane] = lmax;
    __syncthreads();
    if (t < 8) sm[t] = fmaxf(fmaxf(wred[0][t], wred[1][t]), fmaxf(wred[2][t], wred[3][t]));
    __syncthreads();
    float mh = sm[h];
    // pass 2: per-head sum of exp
    float lsum = 0.f;
    for (int i = t; i < deg*8; i += 256){
        int e = i >> 3;
        int s = srcs[beg + e];
        lsum += __expf(lrelu(a_s[s*8 + h] + adh) - mh);
    }
    lsum += __shfl_xor(lsum, 8);
    lsum += __shfl_xor(lsum, 16);
    lsum += __shfl_xor(lsum, 32);
    if (lane < 8) wred[wv][lane] = lsum;
    __syncthreads();
    if (t < 8) srz[t] = 1.f / (wred[0][t] + wred[1][t] + wred[2][t] + wred[3][t] + 1e-16f);
    __syncthreads();
    float rzh = srz[h];
    // pass 3: chunked weighted aggregation; thread t owns channel t (head t>>5)
    int ho = t >> 5;
    float acc = 0.f;
    for (int base = 0; base < deg; base += 32){
        int cnt = deg - base; if (cnt > 32) cnt = 32;
        int el = t >> 3;
        if (el < cnt){
            int e = base + el;
            int s = srcs[beg + e];
            wbuf[el][h] = __expf(lrelu(a_s[s*8 + h] + adh) - mh) * rzh;
            if (h == 0) sbuf[el] = s;
        }
        __syncthreads();
        for (int e2 = 0; e2 < cnt; e2++){
            int s = sbuf[e2];
            acc += wbuf[e2][ho] * bf2f(h1[(size_t)s*256 + t]);
        }
        __syncthreads();
    }
    // fused: x2 = elu(acc + b1)
    float v = acc + bf2f(b1[t]);
    x2[(size_t)n*256 + t] = f2bf(v > 0.f ? v : expm1f(v));
}

// ---------------- GEMM2 + attention scalars layer 2 ----------------
__global__ __launch_bounds__(256) void k_gemm2(const bf16* __restrict__ x2,
        const bf16* __restrict__ W2, const bf16* __restrict__ attS,
        const bf16* __restrict__ attD, float* __restrict__ h2,
        float* __restrict__ a2s, float* __restrict__ a2d, int N){
    __shared__ float w2s[256*8];
    __shared__ float xss[32][257];
    int t = threadIdx.x;
    for (int i = t; i < 2048; i += 256) w2s[i] = bf2f(W2[i]);
    int n0 = blockIdx.x * 32;
    int lim = (N - n0) * 256; if (lim > 32*256) lim = 32*256;
    const bf16* xp = x2 + (size_t)n0 * 256;
    for (int i = t; i < 32*256; i += 256)
        xss[i >> 8][i & 255] = (i < lim) ? bf2f(xp[i]) : 0.f;
    __syncthreads();
    int m = t >> 3, o = t & 7;
    float acc = 0.f;
    const float* xr = xss[m];
    for (int k = 0; k < 256; k++) acc += xr[k] * w2s[k*8 + o];
    float ps = acc * bf2f(attS[o]);
    float pd = acc * bf2f(attD[o]);
    ps += __shfl_xor(ps, 1); ps += __shfl_xor(ps, 2); ps += __shfl_xor(ps, 4);
    pd += __shfl_xor(pd, 1); pd += __shfl_xor(pd, 2); pd += __shfl_xor(pd, 4);
    int n = n0 + m;
    if (n < N){
        h2[(size_t)n*8 + o] = acc;
        if (o == 0){ a2s[n] = ps; a2d[n] = pd; }
    }
}

// ---------------- layer-2 edge softmax + aggregation + bias + log_softmax ----------------
__global__ __launch_bounds__(256) void k_edge2(const int* __restrict__ rowptr,
        const int* __restrict__ srcs, const float* __restrict__ a2s,
        const float* __restrict__ a2d, const float* __restrict__ h2,
        const bf16* __restrict__ b2, void* __restrict__ outv,
        const int* __restrict__ flag, int N){
    int t = threadIdx.x;
    int lane = t & 63, wv = t >> 6;
    int n = blockIdx.x*4 + wv;
    if (n >= N) return;
    int beg = rowptr[n], end = rowptr[n+1];
    int deg = end - beg;
    float adh = a2d[n];
    float lmax = -1e30f;
    for (int i = lane; i < deg; i += 64){
        int s = srcs[beg + i];
        lmax = fmaxf(lmax, lrelu(a2s[s] + adh));
    }
    #pragma unroll
    for (int msk = 1; msk < 64; msk <<= 1) lmax = fmaxf(lmax, __shfl_xor(lmax, msk));
    float lsum = 0.f;
    for (int i = lane; i < deg; i += 64){
        int s = srcs[beg + i];
        lsum += __expf(lrelu(a2s[s] + adh) - lmax);
    }
    #pragma unroll
    for (int msk = 1; msk < 64; msk <<= 1) lsum += __shfl_xor(lsum, msk);
    float rz = 1.f / (lsum + 1e-16f);
    int ep = lane >> 3, c = lane & 7;
    float acc = 0.f;
    for (int e = ep; e < deg; e += 8){
        int s = srcs[beg + e];
        float w = __expf(lrelu(a2s[s] + adh) - lmax) * rz;
        acc += w * h2[(size_t)s*8 + c];
    }
    acc += __shfl_xor(acc, 8);
    acc += __shfl_xor(acc, 16);
    acc += __shfl_xor(acc, 32);
    float val = acc + bf2f(b2[c]);
    float mx = val;
    mx = fmaxf(mx, __shfl_xor(mx, 1));
    mx = fmaxf(mx, __shfl_xor(mx, 2));
    mx = fmaxf(mx, __shfl_xor(mx, 4));
    float se = __expf(val - mx);
    se += __shfl_xor(se, 1); se += __shfl_xor(se, 2); se += __shfl_xor(se, 4);
    float r = val - mx - __logf(se);
    if (lane < 8){
        if (*flag) ((bf16*)outv)[(size_t)n*8 + c] = f2bf(r);
        else       ((float*)outv)[(size_t)n*8 + c] = r;
    }
}

extern "C" void kernel_launch(void* const* d_in, const int* in_sizes, int n_in,
                              void* d_out, int out_size, void* d_ws, size_t ws_size,
                              hipStream_t stream) {
    const int* ei = (const int*)d_in[2];
    const int N = in_sizes[0] / 128;
    const int E = in_sizes[2] / 2;
    const int ET = E + N;

    // workspace carve (256B aligned)
    char* p = (char*)d_ws;
    auto alloc = [&](size_t bytes) -> void* {
        char* r = p;
        p += (bytes + 255) & ~(size_t)255;
        return (void*)r;
    };
    int*   flag   = (int*)  alloc(256);
    int*   counts = (int*)  alloc((size_t)N*4);
    int*   rowptr = (int*)  alloc((size_t)(N+1)*4);
    int*   cursor = (int*)  alloc((size_t)N*4);
    int*   srcs   = (int*)  alloc((size_t)ET*4);
    // canonical bf16 copies of all float inputs
    static const int conv_idx[12] = {0,1,3,4,5,6,7,8,9,10,11,12};
    ConvArgs ca;
    bf16* can[13];
    for (int j = 0; j < 12; j++){
        int i = conv_idx[j];
        ca.src[j] = d_in[i];
        ca.n[j]   = in_sizes[i];
        can[i]    = (bf16*)alloc((size_t)in_sizes[i]*2);
        ca.dst[j] = can[i];
    }
    bf16*  h1  = (bf16*) alloc((size_t)N*256*2);
    float* a_s = (float*)alloc((size_t)N*8*4);
    float* a_d = (float*)alloc((size_t)N*8*4);
    bf16*  x2  = (bf16*) alloc((size_t)N*256*2);
    float* h2  = (float*)alloc((size_t)N*8*4);
    float* a2s = (float*)alloc((size_t)N*4);
    float* a2d = (float*)alloc((size_t)N*4);

    k_detect <<<1, 256, 0, stream>>>((const unsigned short*)d_in[0], flag);
    {
        dim3 g(2048, 12);
        k_convert<<<g, 256, 0, stream>>>(ca, flag);
    }
    k_zero   <<<(N + 255)/256, 256, 0, stream>>>(counts, N);
    k_count  <<<(ET + 255)/256, 256, 0, stream>>>(ei, E, N, counts);
    k_scan   <<<1, 1024, 0, stream>>>(counts, rowptr, cursor, N);
    k_scatter<<<(ET + 255)/256, 256, 0, stream>>>(ei, E, N, cursor, srcs);
    k_gemm1  <<<(N + 63)/64, 256, 0, stream>>>(can[0], can[1], can[3], can[4], can[5], h1, N);
    k_att1   <<<N, 256, 0, stream>>>(h1, can[6], can[7], a_s, a_d, N);
    k_edge1  <<<N, 256, 0, stream>>>(rowptr, srcs, a_s, a_d, h1, can[8], x2, N);
    k_gemm2  <<<(N + 31)/32, 256, 0, stream>>>(x2, can[9], can[10], can[11], h2, a2s, a2d, N);
    k_edge2  <<<(N + 3)/4, 256, 0, stream>>>(rowptr, srcs, a2s, a2d, h2, can[12], d_out, flag, N);
}

// Round 3
// 537.397 us; speedup vs baseline: 1.3806x; 1.3806x over previous
//
#include <hip/hip_runtime.h>
#include <hip/hip_bf16.h>

typedef __hip_bfloat16 bf16;
typedef short bf16x8 __attribute__((ext_vector_type(8)));
typedef float f32x4  __attribute__((ext_vector_type(4)));

__device__ __forceinline__ float bf2f(bf16 v){ return __bfloat162float(v); }
__device__ __forceinline__ bf16  f2bf(float f){ return __float2bfloat16(f); }
__device__ __forceinline__ float lrelu(float a){ return a > 0.f ? a : 0.2f*a; }

// ---------------- dtype detection ----------------
__global__ void k_detect(const unsigned short* __restrict__ raw, int* __restrict__ flag){
    int t = threadIdx.x; // 256
    unsigned short w = raw[2*t];
    int e = (w >> 7) & 0xFF;
    int ok = (e >= 90 && e <= 140) ? 1 : 0;
    __shared__ int cnt;
    if (t == 0) cnt = 0;
    __syncthreads();
    atomicAdd(&cnt, ok);
    __syncthreads();
    if (t == 0) *flag = (cnt >= 192) ? 1 : 0;  // 1 = bf16, 0 = f32
}

// ---------------- convert all float tensors to canonical bf16 ----------------
struct ConvArgs {
    const void* src[12];
    bf16* dst[12];
    int n[12];
};

__global__ __launch_bounds__(256) void k_convert(ConvArgs a, const int* __restrict__ flag){
    int ten = blockIdx.y;
    int n = a.n[ten];
    int isb = *flag;
    const void* s = a.src[ten];
    bf16* d = a.dst[ten];
    for (int i = blockIdx.x*256 + threadIdx.x; i < n; i += gridDim.x*256){
        if (isb) d[i] = ((const bf16*)s)[i];
        else     d[i] = f2bf(((const float*)s)[i]);
    }
}

// ---------------- pack W1 into MFMA B-fragment order ----------------
// Bp[((nt*6 + kt)*64 + lane)*8 + j] = W1[(kt*32 + (lane>>4)*8 + j)*256 + nt*16 + (lane&15)]
__global__ void k_pack(const bf16* __restrict__ W1, bf16* __restrict__ Bp){
    int i = blockIdx.x*256 + threadIdx.x;
    if (i >= 16*6*64*8) return;
    int j = i & 7;
    int lane = (i >> 3) & 63;
    int r = i >> 9;
    int kt = r % 6, nt = r / 6;
    int k = kt*32 + (lane >> 4)*8 + j;
    int n = nt*16 + (lane & 15);
    Bp[i] = W1[k*256 + n];
}

// ---------------- CSR build ----------------
__global__ void k_zero(int* __restrict__ p, int n){
    int i = blockIdx.x*256 + threadIdx.x;
    if (i < n) p[i] = 0;
}

__global__ void k_count(const int* __restrict__ ei, int E, int N, int* __restrict__ counts){
    int i = blockIdx.x*256 + threadIdx.x;
    int tot = E + N;
    if (i < tot){
        int dst = (i < E) ? ei[E + i] : (i - E);
        atomicAdd(&counts[dst], 1);
    }
}

// 3-phase parallel exclusive scan of counts[N] -> rowptr[N+1], cursor[N]
__global__ __launch_bounds__(256) void k_scan_local(const int* __restrict__ counts,
        int* __restrict__ rowptr, int* __restrict__ partials, int N){
    __shared__ int sd[256];
    int t = threadIdx.x;
    int i = blockIdx.x*256 + t;
    int v = (i < N) ? counts[i] : 0;
    sd[t] = v;
    __syncthreads();
    #pragma unroll
    for (int off = 1; off < 256; off <<= 1){
        int a = (t >= off) ? sd[t - off] : 0;
        __syncthreads();
        sd[t] += a;
        __syncthreads();
    }
    if (i < N) rowptr[i] = sd[t] - v;     // local exclusive
    if (t == 255) partials[blockIdx.x] = sd[255];
}

__global__ __launch_bounds__(256) void k_scan_part(int* __restrict__ partials,
        int* __restrict__ blockoff, int* __restrict__ rowptrN, int NB){
    __shared__ int sd[256];
    __shared__ int carry;
    int t = threadIdx.x;
    if (t == 0) carry = 0;
    __syncthreads();
    for (int base = 0; base < NB; base += 256){
        int i = base + t;
        int v = (i < NB) ? partials[i] : 0;
        sd[t] = v;
        __syncthreads();
        #pragma unroll
        for (int off = 1; off < 256; off <<= 1){
            int a = (t >= off) ? sd[t - off] : 0;
            __syncthreads();
            sd[t] += a;
            __syncthreads();
        }
        if (i < NB) blockoff[i] = carry + sd[t] - v;
        __syncthreads();
        if (t == 255) carry += sd[255];
        __syncthreads();
    }
    if (t == 0) *rowptrN = carry;
}

__global__ void k_scan_add(int* __restrict__ rowptr, int* __restrict__ cursor,
        const int* __restrict__ blockoff, int N){
    int i = blockIdx.x*256 + threadIdx.x;
    if (i < N){
        int r = rowptr[i] + blockoff[i >> 8];
        rowptr[i] = r;
        cursor[i] = r;
    }
}

__global__ void k_scatter(const int* __restrict__ ei, int E, int N,
        int* __restrict__ cursor, int* __restrict__ srcs){
    int i = blockIdx.x*256 + threadIdx.x;
    int tot = E + N;
    if (i < tot){
        int src, dst;
        if (i < E){ src = ei[i]; dst = ei[E + i]; }
        else      { src = i - E; dst = i - E; }
        int pos = atomicAdd(&cursor[dst], 1);
        srcs[pos] = src;
    }
}

// ---------------- GEMM1 (MFMA, fused embedding) ----------------
// h1[N,256] = [high | elu(low@Wemb+bemb)] @ W1, 64 rows x 256 cols per block.
__global__ __launch_bounds__(256) void k_gemm1(const bf16* __restrict__ high,
        const bf16* __restrict__ low, const bf16* __restrict__ Wemb,
        const bf16* __restrict__ bemb, const bf16* __restrict__ Bp,
        bf16* __restrict__ h1, int N){
    __shared__ short xs[64*200];          // x tile, bf16, padded stride 200 (25.6 KB)
    __shared__ float wem[32*64 + 64];     // Wemb f32 + bemb at [2048..]
    __shared__ short lows[64*34];         // low tile, padded stride 34
    int t = threadIdx.x;
    int m0 = blockIdx.x * 64;
    int rows = N - m0; if (rows > 64) rows = 64;

    for (int i = t; i < 2048; i += 256) wem[i] = bf2f(Wemb[i]);
    if (t < 64) wem[2048 + t] = bf2f(bemb[t]);
    for (int i = t; i < 64*32; i += 256){
        int r = i >> 5, k = i & 31;
        lows[r*34 + k] = (i < rows*32) ? *(const short*)&low[(size_t)m0*32 + i] : 0;
    }
    for (int i = t; i < 64*128; i += 256){
        int r = i >> 7, c = i & 127;
        xs[r*200 + c] = (r < rows) ? *(const short*)&high[(size_t)(m0 + r)*128 + c] : 0;
    }
    __syncthreads();

    // embedding: thread t -> row r = t&63, cols cb..cb+15 (wem reads are wave-broadcast)
    {
        int r = t & 63;
        int cb = (t >> 6) * 16;
        float acc[16];
        #pragma unroll
        for (int j = 0; j < 16; j++) acc[j] = wem[2048 + cb + j];
        for (int k = 0; k < 32; k++){
            bf16 lv16; *(short*)&lv16 = lows[r*34 + k];
            float lv = bf2f(lv16);
            #pragma unroll
            for (int j = 0; j < 16; j++) acc[j] += lv * wem[k*64 + cb + j];
        }
        #pragma unroll
        for (int j = 0; j < 16; j++){
            float v = acc[j];
            bf16 o = f2bf(v > 0.f ? v : expm1f(v));
            xs[r*200 + 128 + cb + j] = *(short*)&o;
        }
    }
    __syncthreads();

    // MFMA: wave w owns cols [w*64, w*64+64); 4 row-tiles x 4 col-tiles of 16x16
    int w = t >> 6, lane = t & 63;
    int m_lo = lane & 15, quad = lane >> 4;
    f32x4 acc[4][4];
    #pragma unroll
    for (int rt = 0; rt < 4; rt++)
        #pragma unroll
        for (int ct = 0; ct < 4; ct++) acc[rt][ct] = (f32x4){0.f,0.f,0.f,0.f};

    for (int kt = 0; kt < 6; kt++){
        bf16x8 a[4], b[4];
        #pragma unroll
        for (int rt = 0; rt < 4; rt++)
            a[rt] = *(const bf16x8*)&xs[(rt*16 + m_lo)*200 + kt*32 + quad*8];
        #pragma unroll
        for (int ct = 0; ct < 4; ct++)
            b[ct] = *(const bf16x8*)&Bp[(size_t)(((w*4 + ct)*6 + kt)*64 + lane)*8];
        #pragma unroll
        for (int rt = 0; rt < 4; rt++)
            #pragma unroll
            for (int ct = 0; ct < 4; ct++)
                acc[rt][ct] = __builtin_amdgcn_mfma_f32_16x16x32_bf16(a[rt], b[ct], acc[rt][ct], 0, 0, 0);
    }

    // epilogue: C layout col=lane&15, row=quad*4+reg
    #pragma unroll
    for (int rt = 0; rt < 4; rt++){
        #pragma unroll
        for (int reg = 0; reg < 4; reg++){
            int m = m0 + rt*16 + quad*4 + reg;
            if (m < N){
                #pragma unroll
                for (int ct = 0; ct < 4; ct++)
                    h1[(size_t)m*256 + w*64 + ct*16 + m_lo] = f2bf(acc[rt][ct][reg]);
            }
        }
    }
}

// ---------------- attention scalars layer 1 ----------------
__global__ __launch_bounds__(256) void k_att1(const bf16* __restrict__ h1,
        const bf16* __restrict__ attS, const bf16* __restrict__ attD,
        float* __restrict__ a_s, float* __restrict__ a_d, int N){
    int n = blockIdx.x;
    int t = threadIdx.x;
    float v = bf2f(h1[(size_t)n*256 + t]);
    float ps = v * bf2f(attS[t]);
    float pd = v * bf2f(attD[t]);
    #pragma unroll
    for (int m = 1; m < 32; m <<= 1){
        ps += __shfl_xor(ps, m);
        pd += __shfl_xor(pd, m);
    }
    if ((t & 31) == 0){
        a_s[n*8 + (t >> 5)] = ps;
        a_d[n*8 + (t >> 5)] = pd;
    }
}

// ---------------- layer-1 edge softmax + aggregation + elu + bias -> x2 (bf16) ----------------
__global__ __launch_bounds__(256) void k_edge1(const int* __restrict__ rowptr,
        const int* __restrict__ srcs, const float* __restrict__ a_s,
        const float* __restrict__ a_d, const bf16* __restrict__ h1,
        const bf16* __restrict__ b1, bf16* __restrict__ x2, int N){
    __shared__ float ad[8], sm[8], srz[8];
    __shared__ float wred[4][8];
    __shared__ float wbuf[32][8];
    __shared__ int   sbuf[32];
    int n = blockIdx.x;
    int t = threadIdx.x;
    int beg = rowptr[n], end = rowptr[n+1];
    int deg = end - beg;
    if (t < 8) ad[t] = a_d[n*8 + t];
    __syncthreads();
    int h = t & 7;
    float adh = ad[h];
    int lane = t & 63, wv = t >> 6;
    float lmax = -1e30f;
    for (int i = t; i < deg*8; i += 256){
        int e = i >> 3;
        int s = srcs[beg + e];
        lmax = fmaxf(lmax, lrelu(a_s[s*8 + h] + adh));
    }
    lmax = fmaxf(lmax, __shfl_xor(lmax, 8));
    lmax = fmaxf(lmax, __shfl_xor(lmax, 16));
    lmax = fmaxf(lmax, __shfl_xor(lmax, 32));
    if (lane < 8) wred[wv][lane] = lmax;
    __syncthreads();
    if (t < 8) sm[t] = fmaxf(fmaxf(wred[0][t], wred[1][t]), fmaxf(wred[2][t], wred[3][t]));
    __syncthreads();
    float mh = sm[h];
    float lsum = 0.f;
    for (int i = t; i < deg*8; i += 256){
        int e = i >> 3;
        int s = srcs[beg + e];
        lsum += __expf(lrelu(a_s[s*8 + h] + adh) - mh);
    }
    lsum += __shfl_xor(lsum, 8);
    lsum += __shfl_xor(lsum, 16);
    lsum += __shfl_xor(lsum, 32);
    if (lane < 8) wred[wv][lane] = lsum;
    __syncthreads();
    if (t < 8) srz[t] = 1.f / (wred[0][t] + wred[1][t] + wred[2][t] + wred[3][t] + 1e-16f);
    __syncthreads();
    float rzh = srz[h];
    int ho = t >> 5;
    float acc = 0.f;
    for (int base = 0; base < deg; base += 32){
        int cnt = deg - base; if (cnt > 32) cnt = 32;
        int el = t >> 3;
        if (el < cnt){
            int e = base + el;
            int s = srcs[beg + e];
            wbuf[el][h] = __expf(lrelu(a_s[s*8 + h] + adh) - mh) * rzh;
            if (h == 0) sbuf[el] = s;
        }
        __syncthreads();
        for (int e2 = 0; e2 < cnt; e2++){
            int s = sbuf[e2];
            acc += wbuf[e2][ho] * bf2f(h1[(size_t)s*256 + t]);
        }
        __syncthreads();
    }
    float v = acc + bf2f(b1[t]);
    x2[(size_t)n*256 + t] = f2bf(v > 0.f ? v : expm1f(v));
}

// ---------------- GEMM2 + attention scalars layer 2 ----------------
__global__ __launch_bounds__(256) void k_gemm2(const bf16* __restrict__ x2,
        const bf16* __restrict__ W2, const bf16* __restrict__ attS,
        const bf16* __restrict__ attD, float* __restrict__ h2,
        float* __restrict__ a2s, float* __restrict__ a2d, int N){
    __shared__ float w2s[256*8];
    __shared__ float xss[32][257];
    int t = threadIdx.x;
    for (int i = t; i < 2048; i += 256) w2s[i] = bf2f(W2[i]);
    int n0 = blockIdx.x * 32;
    int lim = (N - n0) * 256; if (lim > 32*256) lim = 32*256;
    const bf16* xp = x2 + (size_t)n0 * 256;
    for (int i = t; i < 32*256; i += 256)
        xss[i >> 8][i & 255] = (i < lim) ? bf2f(xp[i]) : 0.f;
    __syncthreads();
    int m = t >> 3, o = t & 7;
    float acc = 0.f;
    const float* xr = xss[m];
    for (int k = 0; k < 256; k++) acc += xr[k] * w2s[k*8 + o];
    float ps = acc * bf2f(attS[o]);
    float pd = acc * bf2f(attD[o]);
    ps += __shfl_xor(ps, 1); ps += __shfl_xor(ps, 2); ps += __shfl_xor(ps, 4);
    pd += __shfl_xor(pd, 1); pd += __shfl_xor(pd, 2); pd += __shfl_xor(pd, 4);
    int n = n0 + m;
    if (n < N){
        h2[(size_t)n*8 + o] = acc;
        if (o == 0){ a2s[n] = ps; a2d[n] = pd; }
    }
}

// ---------------- layer-2 edge softmax + aggregation + bias + log_softmax ----------------
__global__ __launch_bounds__(256) void k_edge2(const int* __restrict__ rowptr,
        const int* __restrict__ srcs, const float* __restrict__ a2s,
        const float* __restrict__ a2d, const float* __restrict__ h2,
        const bf16* __restrict__ b2, void* __restrict__ outv,
        const int* __restrict__ flag, int N){
    int t = threadIdx.x;
    int lane = t & 63, wv = t >> 6;
    int n = blockIdx.x*4 + wv;
    if (n >= N) return;
    int beg = rowptr[n], end = rowptr[n+1];
    int deg = end - beg;
    float adh = a2d[n];
    float lmax = -1e30f;
    for (int i = lane; i < deg; i += 64){
        int s = srcs[beg + i];
        lmax = fmaxf(lmax, lrelu(a2s[s] + adh));
    }
    #pragma unroll
    for (int msk = 1; msk < 64; msk <<= 1) lmax = fmaxf(lmax, __shfl_xor(lmax, msk));
    float lsum = 0.f;
    for (int i = lane; i < deg; i += 64){
        int s = srcs[beg + i];
        lsum += __expf(lrelu(a2s[s] + adh) - lmax);
    }
    #pragma unroll
    for (int msk = 1; msk < 64; msk <<= 1) lsum += __shfl_xor(lsum, msk);
    float rz = 1.f / (lsum + 1e-16f);
    int ep = lane >> 3, c = lane & 7;
    float acc = 0.f;
    for (int e = ep; e < deg; e += 8){
        int s = srcs[beg + e];
        float w = __expf(lrelu(a2s[s] + adh) - lmax) * rz;
        acc += w * h2[(size_t)s*8 + c];
    }
    acc += __shfl_xor(acc, 8);
    acc += __shfl_xor(acc, 16);
    acc += __shfl_xor(acc, 32);
    float val = acc + bf2f(b2[c]);
    float mx = val;
    mx = fmaxf(mx, __shfl_xor(mx, 1));
    mx = fmaxf(mx, __shfl_xor(mx, 2));
    mx = fmaxf(mx, __shfl_xor(mx, 4));
    float se = __expf(val - mx);
    se += __shfl_xor(se, 1); se += __shfl_xor(se, 2); se += __shfl_xor(se, 4);
    float r = val - mx - __logf(se);
    if (lane < 8){
        if (*flag) ((bf16*)outv)[(size_t)n*8 + c] = f2bf(r);
        else       ((float*)outv)[(size_t)n*8 + c] = r;
    }
}

extern "C" void kernel_launch(void* const* d_in, const int* in_sizes, int n_in,
                              void* d_out, int out_size, void* d_ws, size_t ws_size,
                              hipStream_t stream) {
    const int* ei = (const int*)d_in[2];
    const int N = in_sizes[0] / 128;
    const int E = in_sizes[2] / 2;
    const int ET = E + N;
    const int NB = (N + 255) / 256;

    char* p = (char*)d_ws;
    auto alloc = [&](size_t bytes) -> void* {
        char* r = p;
        p += (bytes + 255) & ~(size_t)255;
        return (void*)r;
    };
    int*   flag     = (int*)  alloc(256);
    int*   counts   = (int*)  alloc((size_t)N*4);
    int*   rowptr   = (int*)  alloc((size_t)(N+1)*4);
    int*   cursor   = (int*)  alloc((size_t)N*4);
    int*   srcs     = (int*)  alloc((size_t)ET*4);
    int*   partials = (int*)  alloc((size_t)NB*4);
    int*   blockoff = (int*)  alloc((size_t)NB*4);
    bf16*  Bp       = (bf16*) alloc((size_t)192*256*2);
    static const int conv_idx[12] = {0,1,3,4,5,6,7,8,9,10,11,12};
    ConvArgs ca;
    bf16* can[13];
    for (int j = 0; j < 12; j++){
        int i = conv_idx[j];
        ca.src[j] = d_in[i];
        ca.n[j]   = in_sizes[i];
        can[i]    = (bf16*)alloc((size_t)in_sizes[i]*2);
        ca.dst[j] = can[i];
    }
    bf16*  h1  = (bf16*) alloc((size_t)N*256*2);
    float* a_s = (float*)alloc((size_t)N*8*4);
    float* a_d = (float*)alloc((size_t)N*8*4);
    bf16*  x2  = (bf16*) alloc((size_t)N*256*2);
    float* h2  = (float*)alloc((size_t)N*8*4);
    float* a2s = (float*)alloc((size_t)N*4);
    float* a2d = (float*)alloc((size_t)N*4);

    k_detect <<<1, 256, 0, stream>>>((const unsigned short*)d_in[0], flag);
    {
        dim3 g(2048, 12);
        k_convert<<<g, 256, 0, stream>>>(ca, flag);
    }
    k_pack   <<<192, 256, 0, stream>>>(can[5], Bp);
    k_zero   <<<(N + 255)/256, 256, 0, stream>>>(counts, N);
    k_count  <<<(ET + 255)/256, 256, 0, stream>>>(ei, E, N, counts);
    k_scan_local<<<NB, 256, 0, stream>>>(counts, rowptr, partials, N);
    k_scan_part <<<1, 256, 0, stream>>>(partials, blockoff, rowptr + N, NB);
    k_scan_add  <<<NB, 256, 0, stream>>>(rowptr, cursor, blockoff, N);
    k_scatter<<<(ET + 255)/256, 256, 0, stream>>>(ei, E, N, cursor, srcs);
    k_gemm1  <<<(N + 63)/64, 256, 0, stream>>>(can[0], can[1], can[3], can[4], Bp, h1, N);
    k_att1   <<<N, 256, 0, stream>>>(h1, can[6], can[7], a_s, a_d, N);
    k_edge1  <<<N, 256, 0, stream>>>(rowptr, srcs, a_s, a_d, h1, can[8], x2, N);
    k_gemm2  <<<(N + 31)/32, 256, 0, stream>>>(x2, can[9], can[10], can[11], h2, a2s, a2d, N);
    k_edge2  <<<(N + 3)/4, 256, 0, stream>>>(rowptr, srcs, a2s, a2d, h2, can[12], d_out, flag, N);
}

// Round 4
// 483.779 us; speedup vs baseline: 1.5336x; 1.1108x over previous
//
#include <hip/hip_runtime.h>
#include <hip/hip_bf16.h>

typedef __hip_bfloat16 bf16;
typedef short bf16x8 __attribute__((ext_vector_type(8)));
typedef float f32x4  __attribute__((ext_vector_type(4)));

__device__ __forceinline__ float bf2f(bf16 v){ return __bfloat162float(v); }
__device__ __forceinline__ bf16  f2bf(float f){ return __float2bfloat16(f); }
__device__ __forceinline__ float lrelu(float a){ return a > 0.f ? a : 0.2f*a; }
__device__ __forceinline__ float bfbits(short s){
    union{unsigned u; float f;} cv; cv.u = ((unsigned)(unsigned short)s) << 16; return cv.f;
}

// ---------------- dtype detection ----------------
__global__ void k_detect(const unsigned short* __restrict__ raw, int* __restrict__ flag){
    int t = threadIdx.x; // 256
    unsigned short w = raw[2*t];
    int e = (w >> 7) & 0xFF;
    int ok = (e >= 90 && e <= 140) ? 1 : 0;
    __shared__ int cnt;
    if (t == 0) cnt = 0;
    __syncthreads();
    atomicAdd(&cnt, ok);
    __syncthreads();
    if (t == 0) *flag = (cnt >= 192) ? 1 : 0;  // 1 = bf16, 0 = f32
}

// ---------------- convert all float tensors to canonical bf16 ----------------
struct ConvArgs {
    const void* src[12];
    bf16* dst[12];
    int n[12];
};

__global__ __launch_bounds__(256) void k_convert(ConvArgs a, const int* __restrict__ flag){
    int ten = blockIdx.y;
    int n = a.n[ten];
    int isb = *flag;
    const void* s = a.src[ten];
    bf16* d = a.dst[ten];
    for (int i = blockIdx.x*256 + threadIdx.x; i < n; i += gridDim.x*256){
        if (isb) d[i] = ((const bf16*)s)[i];
        else     d[i] = f2bf(((const float*)s)[i]);
    }
}

// ---------------- pack W1 into MFMA B-fragment order ----------------
__global__ void k_pack(const bf16* __restrict__ W1, bf16* __restrict__ Bp){
    int i = blockIdx.x*256 + threadIdx.x;
    if (i >= 16*6*64*8) return;
    int j = i & 7;
    int lane = (i >> 3) & 63;
    int r = i >> 9;
    int kt = r % 6, nt = r / 6;
    int k = kt*32 + (lane >> 4)*8 + j;
    int n = nt*16 + (lane & 15);
    Bp[i] = W1[k*256 + n];
}

// ---------------- CSR build ----------------
__global__ void k_zero(int* __restrict__ p, int n){
    int i = blockIdx.x*256 + threadIdx.x;
    if (i < n) p[i] = 0;
}

__global__ void k_count(const int* __restrict__ ei, int E, int N, int* __restrict__ counts){
    int i = blockIdx.x*256 + threadIdx.x;
    int tot = E + N;
    if (i < tot){
        int dst = (i < E) ? ei[E + i] : (i - E);
        atomicAdd(&counts[dst], 1);
    }
}

__global__ __launch_bounds__(256) void k_scan_local(const int* __restrict__ counts,
        int* __restrict__ rowptr, int* __restrict__ partials, int N){
    __shared__ int sd[256];
    int t = threadIdx.x;
    int i = blockIdx.x*256 + t;
    int v = (i < N) ? counts[i] : 0;
    sd[t] = v;
    __syncthreads();
    #pragma unroll
    for (int off = 1; off < 256; off <<= 1){
        int a = (t >= off) ? sd[t - off] : 0;
        __syncthreads();
        sd[t] += a;
        __syncthreads();
    }
    if (i < N) rowptr[i] = sd[t] - v;
    if (t == 255) partials[blockIdx.x] = sd[255];
}

__global__ __launch_bounds__(256) void k_scan_part(int* __restrict__ partials,
        int* __restrict__ blockoff, int* __restrict__ rowptrN, int NB){
    __shared__ int sd[256];
    __shared__ int carry;
    int t = threadIdx.x;
    if (t == 0) carry = 0;
    __syncthreads();
    for (int base = 0; base < NB; base += 256){
        int i = base + t;
        int v = (i < NB) ? partials[i] : 0;
        sd[t] = v;
        __syncthreads();
        #pragma unroll
        for (int off = 1; off < 256; off <<= 1){
            int a = (t >= off) ? sd[t - off] : 0;
            __syncthreads();
            sd[t] += a;
            __syncthreads();
        }
        if (i < NB) blockoff[i] = carry + sd[t] - v;
        __syncthreads();
        if (t == 255) carry += sd[255];
        __syncthreads();
    }
    if (t == 0) *rowptrN = carry;
}

__global__ void k_scan_add(int* __restrict__ rowptr, int* __restrict__ cursor,
        const int* __restrict__ blockoff, int N){
    int i = blockIdx.x*256 + threadIdx.x;
    if (i < N){
        int r = rowptr[i] + blockoff[i >> 8];
        rowptr[i] = r;
        cursor[i] = r;
    }
}

__global__ void k_scatter(const int* __restrict__ ei, int E, int N,
        int* __restrict__ cursor, int* __restrict__ srcs){
    int i = blockIdx.x*256 + threadIdx.x;
    int tot = E + N;
    if (i < tot){
        int src, dst;
        if (i < E){ src = ei[i]; dst = ei[E + i]; }
        else      { src = i - E; dst = i - E; }
        int pos = atomicAdd(&cursor[dst], 1);
        srcs[pos] = src;
    }
}

// ---------------- GEMM1 (MFMA, fused embedding) ----------------
__global__ __launch_bounds__(256) void k_gemm1(const bf16* __restrict__ high,
        const bf16* __restrict__ low, const bf16* __restrict__ Wemb,
        const bf16* __restrict__ bemb, const bf16* __restrict__ Bp,
        bf16* __restrict__ h1, int N){
    __shared__ short xs[64*200];
    __shared__ float wem[32*64 + 64];
    __shared__ short lows[64*34];
    int t = threadIdx.x;
    int m0 = blockIdx.x * 64;
    int rows = N - m0; if (rows > 64) rows = 64;

    for (int i = t; i < 2048; i += 256) wem[i] = bf2f(Wemb[i]);
    if (t < 64) wem[2048 + t] = bf2f(bemb[t]);
    for (int i = t; i < 64*32; i += 256){
        int r = i >> 5, k = i & 31;
        lows[r*34 + k] = (i < rows*32) ? *(const short*)&low[(size_t)m0*32 + i] : 0;
    }
    for (int i = t; i < 64*128; i += 256){
        int r = i >> 7, c = i & 127;
        xs[r*200 + c] = (r < rows) ? *(const short*)&high[(size_t)(m0 + r)*128 + c] : 0;
    }
    __syncthreads();

    {
        int r = t & 63;
        int cb = (t >> 6) * 16;
        float acc[16];
        #pragma unroll
        for (int j = 0; j < 16; j++) acc[j] = wem[2048 + cb + j];
        for (int k = 0; k < 32; k++){
            bf16 lv16; *(short*)&lv16 = lows[r*34 + k];
            float lv = bf2f(lv16);
            #pragma unroll
            for (int j = 0; j < 16; j++) acc[j] += lv * wem[k*64 + cb + j];
        }
        #pragma unroll
        for (int j = 0; j < 16; j++){
            float v = acc[j];
            bf16 o = f2bf(v > 0.f ? v : expm1f(v));
            xs[r*200 + 128 + cb + j] = *(short*)&o;
        }
    }
    __syncthreads();

    int w = t >> 6, lane = t & 63;
    int m_lo = lane & 15, quad = lane >> 4;
    f32x4 acc[4][4];
    #pragma unroll
    for (int rt = 0; rt < 4; rt++)
        #pragma unroll
        for (int ct = 0; ct < 4; ct++) acc[rt][ct] = (f32x4){0.f,0.f,0.f,0.f};

    for (int kt = 0; kt < 6; kt++){
        bf16x8 a[4], b[4];
        #pragma unroll
        for (int rt = 0; rt < 4; rt++)
            a[rt] = *(const bf16x8*)&xs[(rt*16 + m_lo)*200 + kt*32 + quad*8];
        #pragma unroll
        for (int ct = 0; ct < 4; ct++)
            b[ct] = *(const bf16x8*)&Bp[(size_t)(((w*4 + ct)*6 + kt)*64 + lane)*8];
        #pragma unroll
        for (int rt = 0; rt < 4; rt++)
            #pragma unroll
            for (int ct = 0; ct < 4; ct++)
                acc[rt][ct] = __builtin_amdgcn_mfma_f32_16x16x32_bf16(a[rt], b[ct], acc[rt][ct], 0, 0, 0);
    }

    #pragma unroll
    for (int rt = 0; rt < 4; rt++){
        #pragma unroll
        for (int reg = 0; reg < 4; reg++){
            int m = m0 + rt*16 + quad*4 + reg;
            if (m < N){
                #pragma unroll
                for (int ct = 0; ct < 4; ct++)
                    h1[(size_t)m*256 + w*64 + ct*16 + m_lo] = f2bf(acc[rt][ct][reg]);
            }
        }
    }
}

// ---------------- attention scalars layer 1 ----------------
__global__ __launch_bounds__(256) void k_att1(const bf16* __restrict__ h1,
        const bf16* __restrict__ attS, const bf16* __restrict__ attD,
        float* __restrict__ a_s, float* __restrict__ a_d, int N){
    int n = blockIdx.x;
    int t = threadIdx.x;
    float v = bf2f(h1[(size_t)n*256 + t]);
    float ps = v * bf2f(attS[t]);
    float pd = v * bf2f(attD[t]);
    #pragma unroll
    for (int m = 1; m < 32; m <<= 1){
        ps += __shfl_xor(ps, m);
        pd += __shfl_xor(pd, m);
    }
    if ((t & 31) == 0){
        a_s[n*8 + (t >> 5)] = ps;
        a_d[n*8 + (t >> 5)] = pd;
    }
}

// ---------------- layer-1 edge softmax + aggregation + elu + bias -> x2 (bf16) ----------------
// One wave per node: no LDS, no __syncthreads.
__global__ __launch_bounds__(256) void k_edge1(const int* __restrict__ rowptr,
        const int* __restrict__ srcs, const float* __restrict__ a_s,
        const float* __restrict__ a_d, const bf16* __restrict__ h1,
        const bf16* __restrict__ b1, bf16* __restrict__ x2, int N){
    int t = threadIdx.x;
    int lane = t & 63, wv = t >> 6;
    int n = blockIdx.x*4 + wv;
    if (n >= N) return;
    int beg = rowptr[n], end = rowptr[n+1];
    int deg = end - beg;

    // pass A: per-head max then sum; lane owns head h = lane&7, edges stride 8
    int h = lane & 7;
    float adh = a_d[n*8 + h];
    float m = -1e30f;
    for (int e = lane >> 3; e < deg; e += 8){
        int s = srcs[beg + e];
        m = fmaxf(m, lrelu(a_s[s*8 + h] + adh));
    }
    m = fmaxf(m, __shfl_xor(m, 8));
    m = fmaxf(m, __shfl_xor(m, 16));
    m = fmaxf(m, __shfl_xor(m, 32));
    float z = 0.f;
    for (int e = lane >> 3; e < deg; e += 8){
        int s = srcs[beg + e];
        z += __expf(lrelu(a_s[s*8 + h] + adh) - m);
    }
    z += __shfl_xor(z, 8);
    z += __shfl_xor(z, 16);
    z += __shfl_xor(z, 32);
    float rz = 1.f / (z + 1e-16f);

    // pass B: half-wave per edge; lane owns channels cl*8..cl*8+7 (head hb = cl>>2)
    int cl = lane & 31;
    int hb = cl >> 2;
    float mh  = __shfl(m, hb);     // lane hb holds head hb's reduced value
    float rzb = __shfl(rz, hb);
    float adb = __shfl(adh, hb);
    int half = lane >> 5;
    float acc[8];
    #pragma unroll
    for (int j = 0; j < 8; j++) acc[j] = 0.f;
    for (int e = half; e < deg; e += 2){
        int s = srcs[beg + e];
        float w = __expf(lrelu(a_s[s*8 + hb] + adb) - mh) * rzb;
        bf16x8 hv = *(const bf16x8*)&h1[(size_t)s*256 + cl*8];
        #pragma unroll
        for (int j = 0; j < 8; j++)
            acc[j] += w * bfbits(hv[j]);
    }
    #pragma unroll
    for (int j = 0; j < 8; j++) acc[j] += __shfl_xor(acc[j], 32);

    if (half == 0){
        bf16x8 bv = *(const bf16x8*)&b1[cl*8];
        bf16 ov[8];
        #pragma unroll
        for (int j = 0; j < 8; j++){
            float v = acc[j] + bfbits(bv[j]);
            ov[j] = f2bf(v > 0.f ? v : expm1f(v));
        }
        *(bf16x8*)&x2[(size_t)n*256 + cl*8] = *(const bf16x8*)ov;
    }
}

// ---------------- GEMM2 + attention scalars layer 2 ----------------
__global__ __launch_bounds__(256) void k_gemm2(const bf16* __restrict__ x2,
        const bf16* __restrict__ W2, const bf16* __restrict__ attS,
        const bf16* __restrict__ attD, float* __restrict__ h2,
        float* __restrict__ a2s, float* __restrict__ a2d, int N){
    __shared__ float w2s[256*8];
    __shared__ float xss[32][257];
    int t = threadIdx.x;
    for (int i = t; i < 2048; i += 256) w2s[i] = bf2f(W2[i]);
    int n0 = blockIdx.x * 32;
    int lim = (N - n0) * 256; if (lim > 32*256) lim = 32*256;
    const bf16* xp = x2 + (size_t)n0 * 256;
    for (int i = t; i < 32*256; i += 256)
        xss[i >> 8][i & 255] = (i < lim) ? bf2f(xp[i]) : 0.f;
    __syncthreads();
    int m = t >> 3, o = t & 7;
    float acc = 0.f;
    const float* xr = xss[m];
    for (int k = 0; k < 256; k++) acc += xr[k] * w2s[k*8 + o];
    float ps = acc * bf2f(attS[o]);
    float pd = acc * bf2f(attD[o]);
    ps += __shfl_xor(ps, 1); ps += __shfl_xor(ps, 2); ps += __shfl_xor(ps, 4);
    pd += __shfl_xor(pd, 1); pd += __shfl_xor(pd, 2); pd += __shfl_xor(pd, 4);
    int n = n0 + m;
    if (n < N){
        h2[(size_t)n*8 + o] = acc;
        if (o == 0){ a2s[n] = ps; a2d[n] = pd; }
    }
}

// ---------------- layer-2 edge softmax + aggregation + bias + log_softmax ----------------
__global__ __launch_bounds__(256) void k_edge2(const int* __restrict__ rowptr,
        const int* __restrict__ srcs, const float* __restrict__ a2s,
        const float* __restrict__ a2d, const float* __restrict__ h2,
        const bf16* __restrict__ b2, void* __restrict__ outv,
        const int* __restrict__ flag, int N){
    int t = threadIdx.x;
    int lane = t & 63, wv = t >> 6;
    int n = blockIdx.x*4 + wv;
    if (n >= N) return;
    int beg = rowptr[n], end = rowptr[n+1];
    int deg = end - beg;
    float adh = a2d[n];
    float lmax = -1e30f;
    for (int i = lane; i < deg; i += 64){
        int s = srcs[beg + i];
        lmax = fmaxf(lmax, lrelu(a2s[s] + adh));
    }
    #pragma unroll
    for (int msk = 1; msk < 64; msk <<= 1) lmax = fmaxf(lmax, __shfl_xor(lmax, msk));
    float lsum = 0.f;
    for (int i = lane; i < deg; i += 64){
        int s = srcs[beg + i];
        lsum += __expf(lrelu(a2s[s] + adh) - lmax);
    }
    #pragma unroll
    for (int msk = 1; msk < 64; msk <<= 1) lsum += __shfl_xor(lsum, msk);
    float rz = 1.f / (lsum + 1e-16f);
    int ep = lane >> 3, c = lane & 7;
    float acc = 0.f;
    for (int e = ep; e < deg; e += 8){
        int s = srcs[beg + e];
        float w = __expf(lrelu(a2s[s] + adh) - lmax) * rz;
        acc += w * h2[(size_t)s*8 + c];
    }
    acc += __shfl_xor(acc, 8);
    acc += __shfl_xor(acc, 16);
    acc += __shfl_xor(acc, 32);
    float val = acc + bf2f(b2[c]);
    float mx = val;
    mx = fmaxf(mx, __shfl_xor(mx, 1));
    mx = fmaxf(mx, __shfl_xor(mx, 2));
    mx = fmaxf(mx, __shfl_xor(mx, 4));
    float se = __expf(val - mx);
    se += __shfl_xor(se, 1); se += __shfl_xor(se, 2); se += __shfl_xor(se, 4);
    float r = val - mx - __logf(se);
    if (lane < 8){
        if (*flag) ((bf16*)outv)[(size_t)n*8 + c] = f2bf(r);
        else       ((float*)outv)[(size_t)n*8 + c] = r;
    }
}

extern "C" void kernel_launch(void* const* d_in, const int* in_sizes, int n_in,
                              void* d_out, int out_size, void* d_ws, size_t ws_size,
                              hipStream_t stream) {
    const int* ei = (const int*)d_in[2];
    const int N = in_sizes[0] / 128;
    const int E = in_sizes[2] / 2;
    const int ET = E + N;
    const int NB = (N + 255) / 256;

    char* p = (char*)d_ws;
    auto alloc = [&](size_t bytes) -> void* {
        char* r = p;
        p += (bytes + 255) & ~(size_t)255;
        return (void*)r;
    };
    int*   flag     = (int*)  alloc(256);
    int*   counts   = (int*)  alloc((size_t)N*4);
    int*   rowptr   = (int*)  alloc((size_t)(N+1)*4);
    int*   cursor   = (int*)  alloc((size_t)N*4);
    int*   srcs     = (int*)  alloc((size_t)ET*4);
    int*   partials = (int*)  alloc((size_t)NB*4);
    int*   blockoff = (int*)  alloc((size_t)NB*4);
    bf16*  Bp       = (bf16*) alloc((size_t)192*256*2);
    static const int conv_idx[12] = {0,1,3,4,5,6,7,8,9,10,11,12};
    ConvArgs ca;
    bf16* can[13];
    for (int j = 0; j < 12; j++){
        int i = conv_idx[j];
        ca.src[j] = d_in[i];
        ca.n[j]   = in_sizes[i];
        can[i]    = (bf16*)alloc((size_t)in_sizes[i]*2);
        ca.dst[j] = can[i];
    }
    bf16*  h1  = (bf16*) alloc((size_t)N*256*2);
    float* a_s = (float*)alloc((size_t)N*8*4);
    float* a_d = (float*)alloc((size_t)N*8*4);
    bf16*  x2  = (bf16*) alloc((size_t)N*256*2);
    float* h2  = (float*)alloc((size_t)N*8*4);
    float* a2s = (float*)alloc((size_t)N*4);
    float* a2d = (float*)alloc((size_t)N*4);

    k_detect <<<1, 256, 0, stream>>>((const unsigned short*)d_in[0], flag);
    {
        dim3 g(2048, 12);
        k_convert<<<g, 256, 0, stream>>>(ca, flag);
    }
    k_pack   <<<192, 256, 0, stream>>>(can[5], Bp);
    k_zero   <<<(N + 255)/256, 256, 0, stream>>>(counts, N);
    k_count  <<<(ET + 255)/256, 256, 0, stream>>>(ei, E, N, counts);
    k_scan_local<<<NB, 256, 0, stream>>>(counts, rowptr, partials, N);
    k_scan_part <<<1, 256, 0, stream>>>(partials, blockoff, rowptr + N, NB);
    k_scan_add  <<<NB, 256, 0, stream>>>(rowptr, cursor, blockoff, N);
    k_scatter<<<(ET + 255)/256, 256, 0, stream>>>(ei, E, N, cursor, srcs);
    k_gemm1  <<<(N + 63)/64, 256, 0, stream>>>(can[0], can[1], can[3], can[4], Bp, h1, N);
    k_att1   <<<N, 256, 0, stream>>>(h1, can[6], can[7], a_s, a_d, N);
    k_edge1  <<<(N + 3)/4, 256, 0, stream>>>(rowptr, srcs, a_s, a_d, h1, can[8], x2, N);
    k_gemm2  <<<(N + 31)/32, 256, 0, stream>>>(x2, can[9], can[10], can[11], h2, a2s, a2d, N);
    k_edge2  <<<(N + 3)/4, 256, 0, stream>>>(rowptr, srcs, a2s, a2d, h2, can[12], d_out, flag, N);
}

// Round 5
// 407.673 us; speedup vs baseline: 1.8199x; 1.1867x over previous
//
#include <hip/hip_runtime.h>
#include <hip/hip_bf16.h>

typedef __hip_bfloat16 bf16;
typedef short bf16x8 __attribute__((ext_vector_type(8)));
typedef float f32x4  __attribute__((ext_vector_type(4)));

__device__ __forceinline__ float bf2f(bf16 v){ return __bfloat162float(v); }
__device__ __forceinline__ bf16  f2bf(float f){ return __float2bfloat16(f); }
__device__ __forceinline__ float lrelu(float a){ return a > 0.f ? a : 0.2f*a; }
__device__ __forceinline__ float bfbits(short s){
    union{unsigned u; float f;} cv; cv.u = ((unsigned)(unsigned short)s) << 16; return cv.f;
}
__device__ __forceinline__ short bf16s(float f){ bf16 q = f2bf(f); return *(short*)&q; }

// ---------------- dtype detection ----------------
__global__ void k_detect(const unsigned short* __restrict__ raw, int* __restrict__ flag){
    int t = threadIdx.x; // 256
    unsigned short w = raw[2*t];
    int e = (w >> 7) & 0xFF;
    int ok = (e >= 90 && e <= 140) ? 1 : 0;
    __shared__ int cnt;
    if (t == 0) cnt = 0;
    __syncthreads();
    atomicAdd(&cnt, ok);
    __syncthreads();
    if (t == 0) *flag = (cnt >= 192) ? 1 : 0;  // 1 = bf16, 0 = f32
}

// ---------------- convert all float tensors to canonical bf16 ----------------
struct ConvArgs {
    const void* src[12];
    bf16* dst[12];
    int n[12];
};

__global__ __launch_bounds__(256) void k_convert(ConvArgs a, const int* __restrict__ flag){
    int ten = blockIdx.y;
    int n = a.n[ten];
    int isb = *flag;
    const void* s = a.src[ten];
    bf16* d = a.dst[ten];
    for (int i = blockIdx.x*256 + threadIdx.x; i < n; i += gridDim.x*256){
        if (isb) d[i] = ((const bf16*)s)[i];
        else     d[i] = f2bf(((const float*)s)[i]);
    }
}

// ---------------- pack W1 into MFMA B-fragment order ----------------
__global__ void k_pack(const bf16* __restrict__ W1, bf16* __restrict__ Bp){
    int i = blockIdx.x*256 + threadIdx.x;
    if (i >= 16*6*64*8) return;
    int j = i & 7;
    int lane = (i >> 3) & 63;
    int r = i >> 9;
    int kt = r % 6, nt = r / 6;
    int k = kt*32 + (lane >> 4)*8 + j;
    int n = nt*16 + (lane & 15);
    Bp[i] = W1[k*256 + n];
}

// ---------------- pack W2 (256x8) into B-fragment order, zero-pad cols 8..15 ----------------
__global__ void k_pack2(const bf16* __restrict__ W2, bf16* __restrict__ Bp2){
    int i = blockIdx.x*256 + threadIdx.x;
    if (i >= 8*64*8) return;
    int j = i & 7;
    int lane = (i >> 3) & 63;
    int kt = i >> 9;
    int k = kt*32 + (lane >> 4)*8 + j;
    int n = lane & 15;
    bf16 z; *(short*)&z = 0;
    Bp2[i] = (n < 8) ? W2[k*8 + n] : z;
}

// ---------------- CSR build ----------------
__global__ void k_zero(int* __restrict__ p, int n){
    int i = blockIdx.x*256 + threadIdx.x;
    if (i < n) p[i] = 0;
}

__global__ void k_count(const int* __restrict__ ei, int E, int N, int* __restrict__ counts){
    int i = blockIdx.x*256 + threadIdx.x;
    int tot = E + N;
    if (i < tot){
        int dst = (i < E) ? ei[E + i] : (i - E);
        atomicAdd(&counts[dst], 1);
    }
}

__global__ __launch_bounds__(256) void k_scan_local(const int* __restrict__ counts,
        int* __restrict__ rowptr, int* __restrict__ partials, int N){
    __shared__ int sd[256];
    int t = threadIdx.x;
    int i = blockIdx.x*256 + t;
    int v = (i < N) ? counts[i] : 0;
    sd[t] = v;
    __syncthreads();
    #pragma unroll
    for (int off = 1; off < 256; off <<= 1){
        int a = (t >= off) ? sd[t - off] : 0;
        __syncthreads();
        sd[t] += a;
        __syncthreads();
    }
    if (i < N) rowptr[i] = sd[t] - v;
    if (t == 255) partials[blockIdx.x] = sd[255];
}

__global__ __launch_bounds__(256) void k_scan_part(int* __restrict__ partials,
        int* __restrict__ blockoff, int* __restrict__ rowptrN, int NB){
    __shared__ int sd[256];
    __shared__ int carry;
    int t = threadIdx.x;
    if (t == 0) carry = 0;
    __syncthreads();
    for (int base = 0; base < NB; base += 256){
        int i = base + t;
        int v = (i < NB) ? partials[i] : 0;
        sd[t] = v;
        __syncthreads();
        #pragma unroll
        for (int off = 1; off < 256; off <<= 1){
            int a = (t >= off) ? sd[t - off] : 0;
            __syncthreads();
            sd[t] += a;
            __syncthreads();
        }
        if (i < NB) blockoff[i] = carry + sd[t] - v;
        __syncthreads();
        if (t == 255) carry += sd[255];
        __syncthreads();
    }
    if (t == 0) *rowptrN = carry;
}

__global__ void k_scan_add(int* __restrict__ rowptr, int* __restrict__ cursor,
        const int* __restrict__ blockoff, int N){
    int i = blockIdx.x*256 + threadIdx.x;
    if (i < N){
        int r = rowptr[i] + blockoff[i >> 8];
        rowptr[i] = r;
        cursor[i] = r;
    }
}

__global__ void k_scatter(const int* __restrict__ ei, int E, int N,
        int* __restrict__ cursor, int* __restrict__ srcs){
    int i = blockIdx.x*256 + threadIdx.x;
    int tot = E + N;
    if (i < tot){
        int src, dst;
        if (i < E){ src = ei[i]; dst = ei[E + i]; }
        else      { src = i - E; dst = i - E; }
        int pos = atomicAdd(&cursor[dst], 1);
        srcs[pos] = src;
    }
}

// ---------------- embedding: emb[N,64] = elu(low@Wemb + bemb) ----------------
__global__ __launch_bounds__(256) void k_emb(const bf16* __restrict__ low,
        const bf16* __restrict__ Wemb, const bf16* __restrict__ bemb,
        bf16* __restrict__ emb, int N){
    __shared__ float wem[2048 + 64];
    __shared__ short lows[1024];
    int t = threadIdx.x;
    int nb = blockIdx.x * 32;
    for (int i = t; i < 2048; i += 256) wem[i] = bf2f(Wemb[i]);
    if (t < 64) wem[2048 + t] = bf2f(bemb[t]);
    int lim = (N - nb) * 32; if (lim > 1024) lim = 1024;
    for (int i = t; i < 1024; i += 256)
        lows[i] = (i < lim) ? *(const short*)&low[(size_t)nb*32 + i] : 0;
    __syncthreads();
    int nl = t >> 3, j8 = (t & 7) * 8;
    float acc[8];
    #pragma unroll
    for (int j = 0; j < 8; j++) acc[j] = wem[2048 + j8 + j];
    for (int k = 0; k < 32; k++){
        float lv = bfbits(lows[nl*32 + k]);
        f32x4 w0 = *(const f32x4*)&wem[k*64 + j8];
        f32x4 w1 = *(const f32x4*)&wem[k*64 + j8 + 4];
        #pragma unroll
        for (int j = 0; j < 4; j++) acc[j]   += lv * w0[j];
        #pragma unroll
        for (int j = 0; j < 4; j++) acc[4+j] += lv * w1[j];
    }
    int n = nb + nl;
    if (n < N){
        short ov[8];
        #pragma unroll
        for (int j = 0; j < 8; j++){
            float v = acc[j];
            ov[j] = bf16s(v > 0.f ? v : expm1f(v));
        }
        *(bf16x8*)&emb[(size_t)n*64 + j8] = *(const bf16x8*)ov;
    }
}

// ---------------- GEMM1 (MFMA, direct-global A/B, fused att scalars) ----------------
// h1[N,256] = [high | emb] @ W1; also a_s/a_d[N,8].
__global__ __launch_bounds__(256, 3) void k_gemm1(const bf16* __restrict__ high,
        const bf16* __restrict__ emb, const bf16* __restrict__ Bp,
        const bf16* __restrict__ attS, const bf16* __restrict__ attD,
        bf16* __restrict__ h1, float* __restrict__ a_s, float* __restrict__ a_d, int N){
    const int RS = 260;                  // padded f32 row stride
    __shared__ float eb[16*260 + 16];    // 16.7 KB bounce buffer
    __shared__ float att[512];
    int t = threadIdx.x;
    att[t] = bf2f(attS[t]);
    att[256 + t] = bf2f(attD[t]);
    int w = t >> 6, lane = t & 63;
    int m_lo = lane & 15, quad = lane >> 4;
    int m0 = blockIdx.x * 64;
    int mr[4];
    #pragma unroll
    for (int rt = 0; rt < 4; rt++){
        int m = m0 + rt*16 + m_lo;
        mr[rt] = m < N ? m : N-1;
    }
    f32x4 acc[4][4];
    #pragma unroll
    for (int rt = 0; rt < 4; rt++)
        #pragma unroll
        for (int ct = 0; ct < 4; ct++) acc[rt][ct] = (f32x4){0.f,0.f,0.f,0.f};

    #pragma unroll 2
    for (int kt = 0; kt < 6; kt++){
        bf16x8 a[4], b[4];
        if (kt < 4){
            #pragma unroll
            for (int rt = 0; rt < 4; rt++)
                a[rt] = *(const bf16x8*)&high[(size_t)mr[rt]*128 + kt*32 + quad*8];
        } else {
            #pragma unroll
            for (int rt = 0; rt < 4; rt++)
                a[rt] = *(const bf16x8*)&emb[(size_t)mr[rt]*64 + (kt-4)*32 + quad*8];
        }
        #pragma unroll
        for (int ct = 0; ct < 4; ct++)
            b[ct] = *(const bf16x8*)&Bp[(size_t)(((w*4 + ct)*6 + kt)*64 + lane)*8];
        #pragma unroll
        for (int rt = 0; rt < 4; rt++)
            #pragma unroll
            for (int ct = 0; ct < 4; ct++)
                acc[rt][ct] = __builtin_amdgcn_mfma_f32_16x16x32_bf16(a[rt], b[ct], acc[rt][ct], 0, 0, 0);
    }

    // epilogue: LDS bounce per 16-row tile -> vectorized stores + att dots
    #pragma unroll 1
    for (int rt = 0; rt < 4; rt++){
        __syncthreads();
        #pragma unroll
        for (int ct = 0; ct < 4; ct++)
            #pragma unroll
            for (int reg = 0; reg < 4; reg++)
                eb[(quad*4 + reg)*RS + w*64 + ct*16 + m_lo] = acc[rt][ct][reg];
        __syncthreads();
        int r = t >> 4, cb = t & 15;
        int c0 = cb * 16;
        int m = m0 + rt*16 + r;
        f32x4 v[4];
        #pragma unroll
        for (int p = 0; p < 4; p++) v[p] = *(const f32x4*)&eb[r*RS + c0 + p*4];
        float ps = 0.f, pd = 0.f;
        #pragma unroll
        for (int p = 0; p < 4; p++)
            #pragma unroll
            for (int j = 0; j < 4; j++){
                ps += v[p][j] * att[c0 + p*4 + j];
                pd += v[p][j] * att[256 + c0 + p*4 + j];
            }
        if (m < N){
            short ov[16];
            #pragma unroll
            for (int p = 0; p < 4; p++)
                #pragma unroll
                for (int j = 0; j < 4; j++) ov[p*4+j] = bf16s(v[p][j]);
            *(bf16x8*)&h1[(size_t)m*256 + c0]     = *(const bf16x8*)&ov[0];
            *(bf16x8*)&h1[(size_t)m*256 + c0 + 8] = *(const bf16x8*)&ov[8];
        }
        ps += __shfl_xor(ps, 1);
        pd += __shfl_xor(pd, 1);
        if (((t & 1) == 0) && m < N){
            int hd = cb >> 1;
            a_s[m*8 + hd] = ps;
            a_d[m*8 + hd] = pd;
        }
    }
}

// ---------------- layer-1 edge softmax + aggregation + elu + bias -> x2 (bf16) ----------------
__global__ __launch_bounds__(256) void k_edge1(const int* __restrict__ rowptr,
        const int* __restrict__ srcs, const float* __restrict__ a_s,
        const float* __restrict__ a_d, const bf16* __restrict__ h1,
        const bf16* __restrict__ b1, bf16* __restrict__ x2, int N){
    int t = threadIdx.x;
    int lane = t & 63, wv = t >> 6;
    int n = blockIdx.x*4 + wv;
    if (n >= N) return;
    int beg = rowptr[n], end = rowptr[n+1];
    int deg = end - beg;

    int h = lane & 7;
    float adh = a_d[n*8 + h];
    float m = -1e30f;
    for (int e = lane >> 3; e < deg; e += 8){
        int s = srcs[beg + e];
        m = fmaxf(m, lrelu(a_s[s*8 + h] + adh));
    }
    m = fmaxf(m, __shfl_xor(m, 8));
    m = fmaxf(m, __shfl_xor(m, 16));
    m = fmaxf(m, __shfl_xor(m, 32));
    float z = 0.f;
    for (int e = lane >> 3; e < deg; e += 8){
        int s = srcs[beg + e];
        z += __expf(lrelu(a_s[s*8 + h] + adh) - m);
    }
    z += __shfl_xor(z, 8);
    z += __shfl_xor(z, 16);
    z += __shfl_xor(z, 32);
    float rz = 1.f / (z + 1e-16f);

    int cl = lane & 31;
    int hb = cl >> 2;
    float mh  = __shfl(m, hb);
    float rzb = __shfl(rz, hb);
    float adb = __shfl(adh, hb);
    int half = lane >> 5;
    float acc[8];
    #pragma unroll
    for (int j = 0; j < 8; j++) acc[j] = 0.f;
    for (int e = half; e < deg; e += 2){
        int s = srcs[beg + e];
        float w = __expf(lrelu(a_s[s*8 + hb] + adb) - mh) * rzb;
        bf16x8 hv = *(const bf16x8*)&h1[(size_t)s*256 + cl*8];
        #pragma unroll
        for (int j = 0; j < 8; j++)
            acc[j] += w * bfbits(hv[j]);
    }
    #pragma unroll
    for (int j = 0; j < 8; j++) acc[j] += __shfl_xor(acc[j], 32);

    if (half == 0){
        bf16x8 bv = *(const bf16x8*)&b1[cl*8];
        short ov[8];
        #pragma unroll
        for (int j = 0; j < 8; j++){
            float v = acc[j] + bfbits(bv[j]);
            ov[j] = bf16s(v > 0.f ? v : expm1f(v));
        }
        *(bf16x8*)&x2[(size_t)n*256 + cl*8] = *(const bf16x8*)ov;
    }
}

// ---------------- GEMM2 (MFMA) + attention scalars layer 2 ----------------
__global__ __launch_bounds__(256) void k_gemm2(const bf16* __restrict__ x2,
        const bf16* __restrict__ Bp2, const bf16* __restrict__ attS,
        const bf16* __restrict__ attD, float* __restrict__ h2,
        float* __restrict__ a2s, float* __restrict__ a2d, int N){
    int t = threadIdx.x;
    int w = t >> 6, lane = t & 63;
    int m_lo = lane & 15, quad = lane >> 4;
    int m0 = blockIdx.x*64 + w*16;
    int mr = m0 + m_lo; if (mr >= N) mr = N-1;
    f32x4 acc = (f32x4){0.f,0.f,0.f,0.f};
    #pragma unroll
    for (int kt = 0; kt < 8; kt++){
        bf16x8 a = *(const bf16x8*)&x2[(size_t)mr*256 + kt*32 + quad*8];
        bf16x8 b = *(const bf16x8*)&Bp2[(size_t)(kt*64 + lane)*8];
        acc = __builtin_amdgcn_mfma_f32_16x16x32_bf16(a, b, acc, 0, 0, 0);
    }
    float s2 = (m_lo < 8) ? bf2f(attS[m_lo]) : 0.f;
    float d2 = (m_lo < 8) ? bf2f(attD[m_lo]) : 0.f;
    #pragma unroll
    for (int reg = 0; reg < 4; reg++){
        int m = m0 + quad*4 + reg;
        float val = acc[reg];
        float ps = val * s2, pd = val * d2;
        ps += __shfl_xor(ps, 1); ps += __shfl_xor(ps, 2);
        ps += __shfl_xor(ps, 4); ps += __shfl_xor(ps, 8);
        pd += __shfl_xor(pd, 1); pd += __shfl_xor(pd, 2);
        pd += __shfl_xor(pd, 4); pd += __shfl_xor(pd, 8);
        if (m < N){
            if (m_lo < 8) h2[(size_t)m*8 + m_lo] = val;
            if (m_lo == 0){ a2s[m] = ps; a2d[m] = pd; }
        }
    }
}

// ---------------- layer-2 edge softmax + aggregation + bias + log_softmax ----------------
__global__ __launch_bounds__(256) void k_edge2(const int* __restrict__ rowptr,
        const int* __restrict__ srcs, const float* __restrict__ a2s,
        const float* __restrict__ a2d, const float* __restrict__ h2,
        const bf16* __restrict__ b2, void* __restrict__ outv,
        const int* __restrict__ flag, int N){
    int t = threadIdx.x;
    int lane = t & 63, wv = t >> 6;
    int n = blockIdx.x*4 + wv;
    if (n >= N) return;
    int beg = rowptr[n], end = rowptr[n+1];
    int deg = end - beg;
    float adh = a2d[n];
    float lmax = -1e30f;
    for (int i = lane; i < deg; i += 64){
        int s = srcs[beg + i];
        lmax = fmaxf(lmax, lrelu(a2s[s] + adh));
    }
    #pragma unroll
    for (int msk = 1; msk < 64; msk <<= 1) lmax = fmaxf(lmax, __shfl_xor(lmax, msk));
    float lsum = 0.f;
    for (int i = lane; i < deg; i += 64){
        int s = srcs[beg + i];
        lsum += __expf(lrelu(a2s[s] + adh) - lmax);
    }
    #pragma unroll
    for (int msk = 1; msk < 64; msk <<= 1) lsum += __shfl_xor(lsum, msk);
    float rz = 1.f / (lsum + 1e-16f);
    int ep = lane >> 3, c = lane & 7;
    float acc = 0.f;
    for (int e = ep; e < deg; e += 8){
        int s = srcs[beg + e];
        float w = __expf(lrelu(a2s[s] + adh) - lmax) * rz;
        acc += w * h2[(size_t)s*8 + c];
    }
    acc += __shfl_xor(acc, 8);
    acc += __shfl_xor(acc, 16);
    acc += __shfl_xor(acc, 32);
    float val = acc + bf2f(b2[c]);
    float mx = val;
    mx = fmaxf(mx, __shfl_xor(mx, 1));
    mx = fmaxf(mx, __shfl_xor(mx, 2));
    mx = fmaxf(mx, __shfl_xor(mx, 4));
    float se = __expf(val - mx);
    se += __shfl_xor(se, 1); se += __shfl_xor(se, 2); se += __shfl_xor(se, 4);
    float r = val - mx - __logf(se);
    if (lane < 8){
        if (*flag) ((bf16*)outv)[(size_t)n*8 + c] = f2bf(r);
        else       ((float*)outv)[(size_t)n*8 + c] = r;
    }
}

extern "C" void kernel_launch(void* const* d_in, const int* in_sizes, int n_in,
                              void* d_out, int out_size, void* d_ws, size_t ws_size,
                              hipStream_t stream) {
    const int* ei = (const int*)d_in[2];
    const int N = in_sizes[0] / 128;
    const int E = in_sizes[2] / 2;
    const int ET = E + N;
    const int NB = (N + 255) / 256;

    char* p = (char*)d_ws;
    auto alloc = [&](size_t bytes) -> void* {
        char* r = p;
        p += (bytes + 255) & ~(size_t)255;
        return (void*)r;
    };
    int*   flag     = (int*)  alloc(256);
    int*   counts   = (int*)  alloc((size_t)N*4);
    int*   rowptr   = (int*)  alloc((size_t)(N+1)*4);
    int*   cursor   = (int*)  alloc((size_t)N*4);
    int*   srcs     = (int*)  alloc((size_t)ET*4);
    int*   partials = (int*)  alloc((size_t)NB*4);
    int*   blockoff = (int*)  alloc((size_t)NB*4);
    bf16*  Bp       = (bf16*) alloc((size_t)192*256*2);
    bf16*  Bp2      = (bf16*) alloc((size_t)8*64*8*2);
    static const int conv_idx[12] = {0,1,3,4,5,6,7,8,9,10,11,12};
    ConvArgs ca;
    bf16* can[13];
    for (int j = 0; j < 12; j++){
        int i = conv_idx[j];
        ca.src[j] = d_in[i];
        ca.n[j]   = in_sizes[i];
        can[i]    = (bf16*)alloc((size_t)in_sizes[i]*2);
        ca.dst[j] = can[i];
    }
    bf16*  emb = (bf16*) alloc((size_t)N*64*2);
    bf16*  h1  = (bf16*) alloc((size_t)N*256*2);
    float* a_s = (float*)alloc((size_t)N*8*4);
    float* a_d = (float*)alloc((size_t)N*8*4);
    bf16*  x2  = (bf16*) alloc((size_t)N*256*2);
    float* h2  = (float*)alloc((size_t)N*8*4);
    float* a2s = (float*)alloc((size_t)N*4);
    float* a2d = (float*)alloc((size_t)N*4);

    k_detect <<<1, 256, 0, stream>>>((const unsigned short*)d_in[0], flag);
    {
        dim3 g(512, 12);
        k_convert<<<g, 256, 0, stream>>>(ca, flag);
    }
    k_pack   <<<192, 256, 0, stream>>>(can[5], Bp);
    k_pack2  <<<16, 256, 0, stream>>>(can[9], Bp2);
    k_zero   <<<(N + 255)/256, 256, 0, stream>>>(counts, N);
    k_count  <<<(ET + 255)/256, 256, 0, stream>>>(ei, E, N, counts);
    k_scan_local<<<NB, 256, 0, stream>>>(counts, rowptr, partials, N);
    k_scan_part <<<1, 256, 0, stream>>>(partials, blockoff, rowptr + N, NB);
    k_scan_add  <<<NB, 256, 0, stream>>>(rowptr, cursor, blockoff, N);
    k_scatter<<<(ET + 255)/256, 256, 0, stream>>>(ei, E, N, cursor, srcs);
    k_emb    <<<(N + 31)/32, 256, 0, stream>>>(can[1], can[3], can[4], emb, N);
    k_gemm1  <<<(N + 63)/64, 256, 0, stream>>>(can[0], emb, Bp, can[6], can[7], h1, a_s, a_d, N);
    k_edge1  <<<(N + 3)/4, 256, 0, stream>>>(rowptr, srcs, a_s, a_d, h1, can[8], x2, N);
    k_gemm2  <<<(N + 63)/64, 256, 0, stream>>>(x2, Bp2, can[10], can[11], h2, a2s, a2d, N);
    k_edge2  <<<(N + 3)/4, 256, 0, stream>>>(rowptr, srcs, a2s, a2d, h2, can[12], d_out, flag, N);
}

// Round 6
// 381.958 us; speedup vs baseline: 1.9424x; 1.0673x over previous
//
#include <hip/hip_runtime.h>
#include <hip/hip_bf16.h>

typedef __hip_bfloat16 bf16;
typedef short bf16x8 __attribute__((ext_vector_type(8)));
typedef float f32x4  __attribute__((ext_vector_type(4)));

__device__ __forceinline__ float bf2f(bf16 v){ return __bfloat162float(v); }
__device__ __forceinline__ bf16  f2bf(float f){ return __float2bfloat16(f); }
__device__ __forceinline__ float lrelu(float a){ return a > 0.f ? a : 0.2f*a; }
__device__ __forceinline__ float bfbits(short s){
    union{unsigned u; float f;} cv; cv.u = ((unsigned)(unsigned short)s) << 16; return cv.f;
}
__device__ __forceinline__ short bf16s(float f){ bf16 q = f2bf(f); return *(short*)&q; }

// ---------------- dtype detection ----------------
__global__ void k_detect(const unsigned short* __restrict__ raw, int* __restrict__ flag){
    int t = threadIdx.x; // 256
    unsigned short w = raw[2*t];
    int e = (w >> 7) & 0xFF;
    int ok = (e >= 90 && e <= 140) ? 1 : 0;
    __shared__ int cnt;
    if (t == 0) cnt = 0;
    __syncthreads();
    atomicAdd(&cnt, ok);
    __syncthreads();
    if (t == 0) *flag = (cnt >= 192) ? 1 : 0;  // 1 = bf16, 0 = f32
}

// ---------------- convert float tensors to canonical bf16 (+ zero counts, slice 12) ----------------
struct ConvArgs {
    const void* src[13];
    bf16* dst[13];
    int n[13];
};

__global__ __launch_bounds__(256) void k_convert(ConvArgs a, const int* __restrict__ flag){
    int ten = blockIdx.y;
    int n = a.n[ten];
    bf16* d = a.dst[ten];
    if (ten == 12){
        bf16 z; *(short*)&z = 0;
        for (int i = blockIdx.x*256 + threadIdx.x; i < n; i += gridDim.x*256)
            d[i] = z;
        return;
    }
    int isb = *flag;
    const void* s = a.src[ten];
    for (int i = blockIdx.x*256 + threadIdx.x; i < n; i += gridDim.x*256){
        if (isb) d[i] = ((const bf16*)s)[i];
        else     d[i] = f2bf(((const float*)s)[i]);
    }
}

// ---------------- pack W1 + W2 into MFMA B-fragment order (merged) ----------------
__global__ void k_packs(const bf16* __restrict__ W1, const bf16* __restrict__ W2,
        bf16* __restrict__ Bp, bf16* __restrict__ Bp2){
    int i = blockIdx.x*256 + threadIdx.x;
    if (i < 16*6*64*8){
        int j = i & 7;
        int lane = (i >> 3) & 63;
        int r = i >> 9;
        int kt = r % 6, nt = r / 6;
        int k = kt*32 + (lane >> 4)*8 + j;
        int n = nt*16 + (lane & 15);
        Bp[i] = W1[k*256 + n];
    } else {
        int i2 = i - 16*6*64*8;
        if (i2 >= 8*64*8) return;
        int j = i2 & 7;
        int lane = (i2 >> 3) & 63;
        int kt = i2 >> 9;
        int k = kt*32 + (lane >> 4)*8 + j;
        int n = lane & 15;
        bf16 z; *(short*)&z = 0;
        Bp2[i2] = (n < 8) ? W2[k*8 + n] : z;
    }
}

// ---------------- CSR build ----------------
__global__ void k_count(const int* __restrict__ ei, int E, int N, int* __restrict__ counts){
    int i = blockIdx.x*256 + threadIdx.x;
    int tot = E + N;
    if (i < tot){
        int dst = (i < E) ? ei[E + i] : (i - E);
        atomicAdd(&counts[dst], 1);
    }
}

__global__ __launch_bounds__(256) void k_scan_local(const int* __restrict__ counts,
        int* __restrict__ rowptr, int* __restrict__ partials, int N){
    __shared__ int sd[256];
    int t = threadIdx.x;
    int i = blockIdx.x*256 + t;
    int v = (i < N) ? counts[i] : 0;
    sd[t] = v;
    __syncthreads();
    #pragma unroll
    for (int off = 1; off < 256; off <<= 1){
        int a = (t >= off) ? sd[t - off] : 0;
        __syncthreads();
        sd[t] += a;
        __syncthreads();
    }
    if (i < N) rowptr[i] = sd[t] - v;
    if (t == 255) partials[blockIdx.x] = sd[255];
}

__global__ __launch_bounds__(256) void k_scan_part(int* __restrict__ partials,
        int* __restrict__ blockoff, int* __restrict__ rowptrN, int NB){
    __shared__ int sd[256];
    __shared__ int carry;
    int t = threadIdx.x;
    if (t == 0) carry = 0;
    __syncthreads();
    for (int base = 0; base < NB; base += 256){
        int i = base + t;
        int v = (i < NB) ? partials[i] : 0;
        sd[t] = v;
        __syncthreads();
        #pragma unroll
        for (int off = 1; off < 256; off <<= 1){
            int a = (t >= off) ? sd[t - off] : 0;
            __syncthreads();
            sd[t] += a;
            __syncthreads();
        }
        if (i < NB) blockoff[i] = carry + sd[t] - v;
        __syncthreads();
        if (t == 255) carry += sd[255];
        __syncthreads();
    }
    if (t == 0) *rowptrN = carry;
}

__global__ void k_scan_add(int* __restrict__ rowptr, int* __restrict__ cursor,
        const int* __restrict__ blockoff, int N){
    int i = blockIdx.x*256 + threadIdx.x;
    if (i < N){
        int r = rowptr[i] + blockoff[i >> 8];
        rowptr[i] = r;
        cursor[i] = r;
    }
}

__global__ void k_scatter(const int* __restrict__ ei, int E, int N,
        int* __restrict__ cursor, int* __restrict__ srcs){
    int i = blockIdx.x*256 + threadIdx.x;
    int tot = E + N;
    if (i < tot){
        int src, dst;
        if (i < E){ src = ei[i]; dst = ei[E + i]; }
        else      { src = i - E; dst = i - E; }
        int pos = atomicAdd(&cursor[dst], 1);
        srcs[pos] = src;
    }
}

// ---------------- embedding: emb[N,64] = elu(low@Wemb + bemb) ----------------
__global__ __launch_bounds__(256) void k_emb(const bf16* __restrict__ low,
        const bf16* __restrict__ Wemb, const bf16* __restrict__ bemb,
        bf16* __restrict__ emb, int N){
    __shared__ float wem[2048 + 64];
    __shared__ short lows[1024];
    int t = threadIdx.x;
    int nb = blockIdx.x * 32;
    for (int i = t; i < 2048; i += 256) wem[i] = bf2f(Wemb[i]);
    if (t < 64) wem[2048 + t] = bf2f(bemb[t]);
    int lim = (N - nb) * 32; if (lim > 1024) lim = 1024;
    for (int i = t; i < 1024; i += 256)
        lows[i] = (i < lim) ? *(const short*)&low[(size_t)nb*32 + i] : 0;
    __syncthreads();
    int nl = t >> 3, j8 = (t & 7) * 8;
    float acc[8];
    #pragma unroll
    for (int j = 0; j < 8; j++) acc[j] = wem[2048 + j8 + j];
    for (int k = 0; k < 32; k++){
        float lv = bfbits(lows[nl*32 + k]);
        f32x4 w0 = *(const f32x4*)&wem[k*64 + j8];
        f32x4 w1 = *(const f32x4*)&wem[k*64 + j8 + 4];
        #pragma unroll
        for (int j = 0; j < 4; j++) acc[j]   += lv * w0[j];
        #pragma unroll
        for (int j = 0; j < 4; j++) acc[4+j] += lv * w1[j];
    }
    int n = nb + nl;
    if (n < N){
        short ov[8];
        #pragma unroll
        for (int j = 0; j < 8; j++){
            float v = acc[j];
            ov[j] = bf16s(v > 0.f ? v : expm1f(v));
        }
        *(bf16x8*)&emb[(size_t)n*64 + j8] = *(const bf16x8*)ov;
    }
}

// ---------------- GEMM1 (MFMA, direct-global A/B, fused att scalars) ----------------
__global__ __launch_bounds__(256, 3) void k_gemm1(const bf16* __restrict__ high,
        const bf16* __restrict__ emb, const bf16* __restrict__ Bp,
        const bf16* __restrict__ attS, const bf16* __restrict__ attD,
        bf16* __restrict__ h1, float* __restrict__ a_s, float* __restrict__ a_d, int N){
    const int RS = 260;
    __shared__ float eb[16*260 + 16];
    __shared__ float att[512];
    int t = threadIdx.x;
    att[t] = bf2f(attS[t]);
    att[256 + t] = bf2f(attD[t]);
    int w = t >> 6, lane = t & 63;
    int m_lo = lane & 15, quad = lane >> 4;
    int m0 = blockIdx.x * 64;
    int mr[4];
    #pragma unroll
    for (int rt = 0; rt < 4; rt++){
        int m = m0 + rt*16 + m_lo;
        mr[rt] = m < N ? m : N-1;
    }
    f32x4 acc[4][4];
    #pragma unroll
    for (int rt = 0; rt < 4; rt++)
        #pragma unroll
        for (int ct = 0; ct < 4; ct++) acc[rt][ct] = (f32x4){0.f,0.f,0.f,0.f};

    #pragma unroll 2
    for (int kt = 0; kt < 6; kt++){
        bf16x8 a[4], b[4];
        if (kt < 4){
            #pragma unroll
            for (int rt = 0; rt < 4; rt++)
                a[rt] = *(const bf16x8*)&high[(size_t)mr[rt]*128 + kt*32 + quad*8];
        } else {
            #pragma unroll
            for (int rt = 0; rt < 4; rt++)
                a[rt] = *(const bf16x8*)&emb[(size_t)mr[rt]*64 + (kt-4)*32 + quad*8];
        }
        #pragma unroll
        for (int ct = 0; ct < 4; ct++)
            b[ct] = *(const bf16x8*)&Bp[(size_t)(((w*4 + ct)*6 + kt)*64 + lane)*8];
        #pragma unroll
        for (int rt = 0; rt < 4; rt++)
            #pragma unroll
            for (int ct = 0; ct < 4; ct++)
                acc[rt][ct] = __builtin_amdgcn_mfma_f32_16x16x32_bf16(a[rt], b[ct], acc[rt][ct], 0, 0, 0);
    }

    #pragma unroll 1
    for (int rt = 0; rt < 4; rt++){
        __syncthreads();
        #pragma unroll
        for (int ct = 0; ct < 4; ct++)
            #pragma unroll
            for (int reg = 0; reg < 4; reg++)
                eb[(quad*4 + reg)*RS + w*64 + ct*16 + m_lo] = acc[rt][ct][reg];
        __syncthreads();
        int r = t >> 4, cb = t & 15;
        int c0 = cb * 16;
        int m = m0 + rt*16 + r;
        f32x4 v[4];
        #pragma unroll
        for (int p = 0; p < 4; p++) v[p] = *(const f32x4*)&eb[r*RS + c0 + p*4];
        float ps = 0.f, pd = 0.f;
        #pragma unroll
        for (int p = 0; p < 4; p++)
            #pragma unroll
            for (int j = 0; j < 4; j++){
                ps += v[p][j] * att[c0 + p*4 + j];
                pd += v[p][j] * att[256 + c0 + p*4 + j];
            }
        if (m < N){
            short ov[16];
            #pragma unroll
            for (int p = 0; p < 4; p++)
                #pragma unroll
                for (int j = 0; j < 4; j++) ov[p*4+j] = bf16s(v[p][j]);
            *(bf16x8*)&h1[(size_t)m*256 + c0]     = *(const bf16x8*)&ov[0];
            *(bf16x8*)&h1[(size_t)m*256 + c0 + 8] = *(const bf16x8*)&ov[8];
        }
        ps += __shfl_xor(ps, 1);
        pd += __shfl_xor(pd, 1);
        if (((t & 1) == 0) && m < N){
            int hd = cb >> 1;
            a_s[m*8 + hd] = ps;
            a_d[m*8 + hd] = pd;
        }
    }
}

// ---------------- layer-1: SINGLE-SWEEP unnormalized softmax aggregate + elu + bias ----------------
// softmax identity: e^a/sum(e^a) == e^(a-m)/sum(e^(a-m)); |alpha| << 80 here, so no max pass.
__global__ __launch_bounds__(256) void k_edge1(const int* __restrict__ rowptr,
        const int* __restrict__ srcs, const float* __restrict__ a_s,
        const float* __restrict__ a_d, const bf16* __restrict__ h1,
        const bf16* __restrict__ b1, bf16* __restrict__ x2, int N){
    int t = threadIdx.x;
    int lane = t & 63, wv = t >> 6;
    int n = blockIdx.x*4 + wv;
    if (n >= N) return;
    int beg = rowptr[n];
    int deg = rowptr[n+1] - beg;

    int cl = lane & 31;          // channel group: channels cl*8..cl*8+7
    int hb = cl >> 2;            // head of this group
    int half = lane >> 5;        // which half-wave (edge parity)
    float adb = a_d[n*8 + hb];

    float acc[8];
    #pragma unroll
    for (int j = 0; j < 8; j++) acc[j] = 0.f;
    float z = 0.f;

    int e = half;
    for (; e + 2 < deg; e += 4){
        int s0 = srcs[beg + e];
        int s1 = srcs[beg + e + 2];
        float w0 = __expf(fminf(lrelu(a_s[s0*8 + hb] + adb), 80.f));
        float w1 = __expf(fminf(lrelu(a_s[s1*8 + hb] + adb), 80.f));
        bf16x8 h0 = *(const bf16x8*)&h1[(size_t)s0*256 + cl*8];
        bf16x8 h1v = *(const bf16x8*)&h1[(size_t)s1*256 + cl*8];
        z += w0 + w1;
        #pragma unroll
        for (int j = 0; j < 8; j++) acc[j] += w0 * bfbits(h0[j]);
        #pragma unroll
        for (int j = 0; j < 8; j++) acc[j] += w1 * bfbits(h1v[j]);
    }
    if (e < deg){
        int s = srcs[beg + e];
        float w = __expf(fminf(lrelu(a_s[s*8 + hb] + adb), 80.f));
        bf16x8 hv = *(const bf16x8*)&h1[(size_t)s*256 + cl*8];
        z += w;
        #pragma unroll
        for (int j = 0; j < 8; j++) acc[j] += w * bfbits(hv[j]);
    }
    // combine halves
    #pragma unroll
    for (int j = 0; j < 8; j++) acc[j] += __shfl_xor(acc[j], 32);
    z += __shfl_xor(z, 32);
    float rz = 1.f / (z + 1e-16f);

    if (half == 0){
        bf16x8 bv = *(const bf16x8*)&b1[cl*8];
        short ov[8];
        #pragma unroll
        for (int j = 0; j < 8; j++){
            float v = acc[j] * rz + bfbits(bv[j]);
            ov[j] = bf16s(v > 0.f ? v : expm1f(v));
        }
        *(bf16x8*)&x2[(size_t)n*256 + cl*8] = *(const bf16x8*)ov;
    }
}

// ---------------- GEMM2 (MFMA) + attention scalars layer 2 ----------------
__global__ __launch_bounds__(256) void k_gemm2(const bf16* __restrict__ x2,
        const bf16* __restrict__ Bp2, const bf16* __restrict__ attS,
        const bf16* __restrict__ attD, float* __restrict__ h2,
        float* __restrict__ a2s, float* __restrict__ a2d, int N){
    int t = threadIdx.x;
    int w = t >> 6, lane = t & 63;
    int m_lo = lane & 15, quad = lane >> 4;
    int m0 = blockIdx.x*64 + w*16;
    int mr = m0 + m_lo; if (mr >= N) mr = N-1;
    f32x4 acc = (f32x4){0.f,0.f,0.f,0.f};
    #pragma unroll
    for (int kt = 0; kt < 8; kt++){
        bf16x8 a = *(const bf16x8*)&x2[(size_t)mr*256 + kt*32 + quad*8];
        bf16x8 b = *(const bf16x8*)&Bp2[(size_t)(kt*64 + lane)*8];
        acc = __builtin_amdgcn_mfma_f32_16x16x32_bf16(a, b, acc, 0, 0, 0);
    }
    float s2 = (m_lo < 8) ? bf2f(attS[m_lo]) : 0.f;
    float d2 = (m_lo < 8) ? bf2f(attD[m_lo]) : 0.f;
    #pragma unroll
    for (int reg = 0; reg < 4; reg++){
        int m = m0 + quad*4 + reg;
        float val = acc[reg];
        float ps = val * s2, pd = val * d2;
        ps += __shfl_xor(ps, 1); ps += __shfl_xor(ps, 2);
        ps += __shfl_xor(ps, 4); ps += __shfl_xor(ps, 8);
        pd += __shfl_xor(pd, 1); pd += __shfl_xor(pd, 2);
        pd += __shfl_xor(pd, 4); pd += __shfl_xor(pd, 8);
        if (m < N){
            if (m_lo < 8) h2[(size_t)m*8 + m_lo] = val;
            if (m_lo == 0){ a2s[m] = ps; a2d[m] = pd; }
        }
    }
}

// ---------------- layer-2: SINGLE-SWEEP aggregate + bias + log_softmax ----------------
__global__ __launch_bounds__(256) void k_edge2(const int* __restrict__ rowptr,
        const int* __restrict__ srcs, const float* __restrict__ a2s,
        const float* __restrict__ a2d, const float* __restrict__ h2,
        const bf16* __restrict__ b2, void* __restrict__ outv,
        const int* __restrict__ flag, int N){
    int t = threadIdx.x;
    int lane = t & 63, wv = t >> 6;
    int n = blockIdx.x*4 + wv;
    if (n >= N) return;
    int beg = rowptr[n];
    int deg = rowptr[n+1] - beg;
    float adh = a2d[n];
    int ep = lane >> 3, c = lane & 7;
    float acc = 0.f, z = 0.f;
    for (int e = ep; e < deg; e += 8){
        int s = srcs[beg + e];
        float w = __expf(fminf(lrelu(a2s[s] + adh), 80.f));
        z += w;
        acc += w * h2[(size_t)s*8 + c];
    }
    acc += __shfl_xor(acc, 8);
    acc += __shfl_xor(acc, 16);
    acc += __shfl_xor(acc, 32);
    z += __shfl_xor(z, 8);
    z += __shfl_xor(z, 16);
    z += __shfl_xor(z, 32);
    float val = acc / (z + 1e-16f) + bf2f(b2[c]);
    float mx = val;
    mx = fmaxf(mx, __shfl_xor(mx, 1));
    mx = fmaxf(mx, __shfl_xor(mx, 2));
    mx = fmaxf(mx, __shfl_xor(mx, 4));
    float se = __expf(val - mx);
    se += __shfl_xor(se, 1); se += __shfl_xor(se, 2); se += __shfl_xor(se, 4);
    float r = val - mx - __logf(se);
    if (lane < 8){
        if (*flag) ((bf16*)outv)[(size_t)n*8 + c] = f2bf(r);
        else       ((float*)outv)[(size_t)n*8 + c] = r;
    }
}

extern "C" void kernel_launch(void* const* d_in, const int* in_sizes, int n_in,
                              void* d_out, int out_size, void* d_ws, size_t ws_size,
                              hipStream_t stream) {
    const int* ei = (const int*)d_in[2];
    const int N = in_sizes[0] / 128;
    const int E = in_sizes[2] / 2;
    const int ET = E + N;
    const int NB = (N + 255) / 256;

    char* p = (char*)d_ws;
    auto alloc = [&](size_t bytes) -> void* {
        char* r = p;
        p += (bytes + 255) & ~(size_t)255;
        return (void*)r;
    };
    int*   flag     = (int*)  alloc(256);
    int*   counts   = (int*)  alloc((size_t)N*4);
    int*   rowptr   = (int*)  alloc((size_t)(N+1)*4);
    int*   cursor   = (int*)  alloc((size_t)N*4);
    int*   srcs     = (int*)  alloc((size_t)ET*4);
    int*   partials = (int*)  alloc((size_t)NB*4);
    int*   blockoff = (int*)  alloc((size_t)NB*4);
    bf16*  Bp       = (bf16*) alloc((size_t)192*256*2);
    bf16*  Bp2      = (bf16*) alloc((size_t)8*64*8*2);
    static const int conv_idx[12] = {0,1,3,4,5,6,7,8,9,10,11,12};
    ConvArgs ca;
    bf16* can[13];
    for (int j = 0; j < 12; j++){
        int i = conv_idx[j];
        ca.src[j] = d_in[i];
        ca.n[j]   = in_sizes[i];
        can[i]    = (bf16*)alloc((size_t)in_sizes[i]*2);
        ca.dst[j] = can[i];
    }
    // slice 12: zero counts (N ints = 2N bf16-zero shorts)
    ca.src[12] = counts;
    ca.dst[12] = (bf16*)counts;
    ca.n[12]   = 2*N;
    bf16*  emb = (bf16*) alloc((size_t)N*64*2);
    bf16*  h1  = (bf16*) alloc((size_t)N*256*2);
    float* a_s = (float*)alloc((size_t)N*8*4);
    float* a_d = (float*)alloc((size_t)N*8*4);
    bf16*  x2  = (bf16*) alloc((size_t)N*256*2);
    float* h2  = (float*)alloc((size_t)N*8*4);
    float* a2s = (float*)alloc((size_t)N*4);
    float* a2d = (float*)alloc((size_t)N*4);

    k_detect <<<1, 256, 0, stream>>>((const unsigned short*)d_in[0], flag);
    {
        dim3 g(512, 13);
        k_convert<<<g, 256, 0, stream>>>(ca, flag);
    }
    k_packs  <<<(16*6*64*8 + 8*64*8 + 255)/256, 256, 0, stream>>>(can[5], can[9], Bp, Bp2);
    k_count  <<<(ET + 255)/256, 256, 0, stream>>>(ei, E, N, counts);
    k_scan_local<<<NB, 256, 0, stream>>>(counts, rowptr, partials, N);
    k_scan_part <<<1, 256, 0, stream>>>(partials, blockoff, rowptr + N, NB);
    k_scan_add  <<<NB, 256, 0, stream>>>(rowptr, cursor, blockoff, N);
    k_scatter<<<(ET + 255)/256, 256, 0, stream>>>(ei, E, N, cursor, srcs);
    k_emb    <<<(N + 31)/32, 256, 0, stream>>>(can[1], can[3], can[4], emb, N);
    k_gemm1  <<<(N + 63)/64, 256, 0, stream>>>(can[0], emb, Bp, can[6], can[7], h1, a_s, a_d, N);
    k_edge1  <<<(N + 3)/4, 256, 0, stream>>>(rowptr, srcs, a_s, a_d, h1, can[8], x2, N);
    k_gemm2  <<<(N + 63)/64, 256, 0, stream>>>(x2, Bp2, can[10], can[11], h2, a2s, a2d, N);
    k_edge2  <<<(N + 3)/4, 256, 0, stream>>>(rowptr, srcs, a2s, a2d, h2, can[12], d_out, flag, N);
}